// Round 5
// baseline (341.500 us; speedup 1.0000x reference)
//
#include <hip/hip_runtime.h>
#include <math.h>

// FFJORD ODE func: 3-layer MLP fwd + VJP + Hutchinson divergence.
// B=262144 rows, D=64, H=256. bf16 MFMA (16x16x32), fp32 accumulate.
// R5: single z/e LDS buffer (stage e after G0) -> 38.9 KB -> 4 blocks/CU
//     (32 waves/CU); bias folded into MFMA C-init; pow2 div in prep_pack.
//
// ws layout:
//   bf16 packed B-fragments (frag = 512 bf16, MFMA B-layout, frag_id = nt*KT+kt):
//     P0 @ elem 0      : fwd L0  B[s<64][n<256]  = W0[n][1+s]   (KT=2,  32 frags)
//     P1 @ elem 16384  : fwd L1  B[s<256][n<256] = W1[n][1+s]   (KT=8, 128 frags)
//     P2 @ elem 81920  : fwd L2  B[s<256][n<64]  = W2[n][1+s]   (KT=8,  32 frags)
//     P3 @ elem 98304  : bwd g2  B[s<64][n<256]  = W2[s][1+n]   (KT=2,  32 frags)
//     P4 @ elem 114688 : bwd g1  B[s<256][n<256] = W1[s][1+n]   (KT=8, 128 frags)
//     P5 @ elem 180224 : bwd g0  B[s<256][n<64]  = W0[s][1+n]   (KT=8,  32 frags)
//   fp32 cst @ byte 393216: cst0[256], cst1[256], cst2[64] = t*W[:,0]+b

typedef __attribute__((ext_vector_type(8))) short short8;
typedef __attribute__((ext_vector_type(4))) float floatx4;

#define NT 512    // 8 waves
#define RB 32
#define LDA 264   // bf16 row stride (528 B; dword stride ≡4 mod 32 -> 2-way alias only)
#define LDZ 72

#define P0_OFF 0
#define P1_OFF 16384
#define P2_OFF 81920
#define P3_OFF 98304
#define P4_OFF 114688
#define P5_OFF 180224
#define PACK_ELEMS 196608
#define CST_BYTE_OFF (PACK_ELEMS * 2)
#define WS_BYTES (CST_BYTE_OFF + 576 * 4)

static __device__ __forceinline__ short f2bf(float f) {
    union { float f; unsigned u; } v; v.f = f;
    unsigned r = v.u + 0x7FFFu + ((v.u >> 16) & 1u);   // RNE
    return (short)(r >> 16);
}
static __device__ __forceinline__ float bf2f(short h) {
    union { unsigned u; float f; } v; v.u = ((unsigned)(unsigned short)h) << 16;
    return v.f;
}
// Fast softplus: native v_exp_f32/v_log_f32; error ~2^-24 abs, invisible at bf16.
static __device__ __forceinline__ float softplus_fast(float x) {
    float u = __expf(-fabsf(x));
    return fmaxf(x, 0.0f) + __logf(1.0f + u);
}

__global__ void prep_pack(const float* __restrict__ t,
                          const float* __restrict__ W0, const float* __restrict__ b0,
                          const float* __restrict__ W1, const float* __restrict__ b1,
                          const float* __restrict__ W2, const float* __restrict__ b2,
                          short* __restrict__ wsp)
{
    int i = blockIdx.x * blockDim.x + threadIdx.x;
    if (i < PACK_ELEMS) {
        int jin, ld, mode, kt, nt; const float* src;
        // branch-local pow2 div/mod (no v_rcp sequences)
        if      (i < P1_OFF) { jin = i - P0_OFF; src = W0; ld = 65;  mode = 0;
                               int f = jin >> 9; kt = f & 1; nt = f >> 1; }
        else if (i < P2_OFF) { jin = i - P1_OFF; src = W1; ld = 257; mode = 0;
                               int f = jin >> 9; kt = f & 7; nt = f >> 3; }
        else if (i < P3_OFF) { jin = i - P2_OFF; src = W2; ld = 257; mode = 0;
                               int f = jin >> 9; kt = f & 7; nt = f >> 3; }
        else if (i < P4_OFF) { jin = i - P3_OFF; src = W2; ld = 257; mode = 1;
                               int f = jin >> 9; kt = f & 1; nt = f >> 1; }
        else if (i < P5_OFF) { jin = i - P4_OFF; src = W1; ld = 257; mode = 1;
                               int f = jin >> 9; kt = f & 7; nt = f >> 3; }
        else                 { jin = i - P5_OFF; src = W0; ld = 65;  mode = 1;
                               int f = jin >> 9; kt = f & 7; nt = f >> 3; }
        int r = jin & 511;
        int lane = r >> 3, jj = r & 7;
        int k = kt * 32 + (lane >> 4) * 8 + jj;
        int n = nt * 16 + (lane & 15);
        float v = (mode == 0) ? src[n * ld + 1 + k] : src[k * ld + 1 + n];
        wsp[i] = f2bf(v);
    } else if (i < PACK_ELEMS + 576) {
        int ci = i - PACK_ELEMS;
        float tv = t[0];
        float* cst = (float*)((char*)wsp + CST_BYTE_OFF);
        float v;
        if (ci < 256)      v = tv * W0[ci * 65] + b0[ci];
        else if (ci < 512) { int n = ci - 256; v = tv * W1[n * 257] + b1[n]; }
        else               { int n = ci - 512; v = tv * W2[n * 257] + b2[n]; }
        cst[ci] = v;
    }
}

__global__ __launch_bounds__(NT, 8)   // 8 waves/EU -> 4 blocks/CU, VGPR cap 64
void ode_mfma(const float* __restrict__ y, const float* __restrict__ e,
              const short* __restrict__ wsp, float* __restrict__ out)
{
    __shared__ __align__(16) short Az[RB * LDZ];   // z bf16, then e bf16 (after G0)
    __shared__ __align__(16) short Ha[RB * LDA];   // h0, then p0 (in place)
    __shared__ __align__(16) short Hb[RB * LDA];   // h1, then p1 (in place)
    __shared__ float divp[4][RB];
    // LDS total: 4608 + 16896 + 16896 + 512 = 38912 B -> 4 blocks/CU

    const int tid = threadIdx.x;
    const int rowbase = blockIdx.x * RB;
    const int w = tid >> 6, l = tid & 63;
    const int lr = l & 15, lq = l >> 4;
    const int ne = w;                    // 256-col GEMMs: wave owns 2 n-tiles, BOTH m-tiles
    const int mt = w & 1, nq = w >> 1;   // 64-col GEMMs
    const float* cst = (const float*)((const char*)wsp + CST_BYTE_OFF);

    // ---- stage z = y[:, :64] ----
    #pragma unroll
    for (int it = 0; it < 4; ++it) {
        int idx = tid + it * NT;            // 0..2047
        int r = idx >> 6, d = idx & 63;
        Az[r * LDZ + d] = f2bf(y[(rowbase + r) * 65 + d]);
    }
    __syncthreads();

    const floatx4 zero = {0.f, 0.f, 0.f, 0.f};

    // ================= G0: h0 = softplus(z @ P0 + cst0) =================
    {
        floatx4 acc[2][2];   // [m][n], C-init = bias fold
        {
            float c0 = cst[(ne * 2 + 0) * 16 + lr];
            float c1 = cst[(ne * 2 + 1) * 16 + lr];
            acc[0][0] = (floatx4){c0, c0, c0, c0}; acc[1][0] = acc[0][0];
            acc[0][1] = (floatx4){c1, c1, c1, c1}; acc[1][1] = acc[0][1];
        }
        const int nt0 = ne * 2;
        #pragma unroll
        for (int kt = 0; kt < 2; ++kt) {
            short8 a0 = *(const short8*)&Az[lr * LDZ + kt * 32 + lq * 8];
            short8 a1 = *(const short8*)&Az[(16 + lr) * LDZ + kt * 32 + lq * 8];
            short8 b0 = *(const short8*)&wsp[P0_OFF + ((nt0 + 0) * 2 + kt) * 512 + l * 8];
            short8 b1 = *(const short8*)&wsp[P0_OFF + ((nt0 + 1) * 2 + kt) * 512 + l * 8];
            acc[0][0] = __builtin_amdgcn_mfma_f32_16x16x32_bf16(a0, b0, acc[0][0], 0, 0, 0);
            acc[0][1] = __builtin_amdgcn_mfma_f32_16x16x32_bf16(a0, b1, acc[0][1], 0, 0, 0);
            acc[1][0] = __builtin_amdgcn_mfma_f32_16x16x32_bf16(a1, b0, acc[1][0], 0, 0, 0);
            acc[1][1] = __builtin_amdgcn_mfma_f32_16x16x32_bf16(a1, b1, acc[1][1], 0, 0, 0);
        }
        #pragma unroll
        for (int m = 0; m < 2; ++m) {
            #pragma unroll
            for (int n = 0; n < 2; ++n) {
                int col = (nt0 + n) * 16 + lr;
                #pragma unroll
                for (int r = 0; r < 4; ++r) {
                    int row = m * 16 + lq * 4 + r;
                    Ha[row * LDA + col] = f2bf(softplus_fast(acc[m][n][r]));
                }
            }
        }
    }
    __syncthreads();

    // ---- stage e -> Az (z dead after G0; e consumed from G3 on) ----
    #pragma unroll
    for (int it = 0; it < 4; ++it) {
        int idx = tid + it * NT;
        int r = idx >> 6, d = idx & 63;
        Az[r * LDZ + d] = f2bf(e[(rowbase + r) * 64 + d]);
    }

    // ================= G1: h1 = softplus(h0 @ P1 + cst1) =================
    {
        floatx4 acc[2][2];
        {
            float c0 = cst[256 + (ne * 2 + 0) * 16 + lr];
            float c1 = cst[256 + (ne * 2 + 1) * 16 + lr];
            acc[0][0] = (floatx4){c0, c0, c0, c0}; acc[1][0] = acc[0][0];
            acc[0][1] = (floatx4){c1, c1, c1, c1}; acc[1][1] = acc[0][1];
        }
        const int nt0 = ne * 2;
        #pragma unroll
        for (int kt = 0; kt < 8; ++kt) {
            short8 a0 = *(const short8*)&Ha[lr * LDA + kt * 32 + lq * 8];
            short8 a1 = *(const short8*)&Ha[(16 + lr) * LDA + kt * 32 + lq * 8];
            short8 b0 = *(const short8*)&wsp[P1_OFF + ((nt0 + 0) * 8 + kt) * 512 + l * 8];
            short8 b1 = *(const short8*)&wsp[P1_OFF + ((nt0 + 1) * 8 + kt) * 512 + l * 8];
            acc[0][0] = __builtin_amdgcn_mfma_f32_16x16x32_bf16(a0, b0, acc[0][0], 0, 0, 0);
            acc[0][1] = __builtin_amdgcn_mfma_f32_16x16x32_bf16(a0, b1, acc[0][1], 0, 0, 0);
            acc[1][0] = __builtin_amdgcn_mfma_f32_16x16x32_bf16(a1, b0, acc[1][0], 0, 0, 0);
            acc[1][1] = __builtin_amdgcn_mfma_f32_16x16x32_bf16(a1, b1, acc[1][1], 0, 0, 0);
        }
        #pragma unroll
        for (int m = 0; m < 2; ++m) {
            #pragma unroll
            for (int n = 0; n < 2; ++n) {
                int col = (nt0 + n) * 16 + lr;
                #pragma unroll
                for (int r = 0; r < 4; ++r) {
                    int row = m * 16 + lq * 4 + r;
                    Hb[row * LDA + col] = f2bf(softplus_fast(acc[m][n][r]));
                }
            }
        }
    }
    __syncthreads();

    // ================= G2: dx = h1 @ P2 + cst2 -> out[:, :64] =================
    {
        floatx4 a0;
        {
            float c = cst[512 + nq * 16 + lr];
            a0 = (floatx4){c, c, c, c};
        }
        #pragma unroll
        for (int kt = 0; kt < 8; ++kt) {
            short8 a = *(const short8*)&Hb[(mt * 16 + lr) * LDA + kt * 32 + lq * 8];
            short8 b = *(const short8*)&wsp[P2_OFF + (nq * 8 + kt) * 512 + l * 8];
            a0 = __builtin_amdgcn_mfma_f32_16x16x32_bf16(a, b, a0, 0, 0, 0);
        }
        int col = nq * 16 + lr;
        #pragma unroll
        for (int r = 0; r < 4; ++r) {
            int row = mt * 16 + lq * 4 + r;
            out[(rowbase + row) * 65 + col] = a0[r];
        }
    }
    __syncthreads();   // all Hb (h1) reads done before G3 overwrites Hb

    // ========= G3: g2 = e @ P3;  p1 = g2 * (1-exp(-h1)) -> Hb IN PLACE =========
    {
        floatx4 acc[2][2];
        acc[0][0] = zero; acc[0][1] = zero; acc[1][0] = zero; acc[1][1] = zero;
        const int nt0 = ne * 2;
        #pragma unroll
        for (int kt = 0; kt < 2; ++kt) {
            short8 a0 = *(const short8*)&Az[lr * LDZ + kt * 32 + lq * 8];
            short8 a1 = *(const short8*)&Az[(16 + lr) * LDZ + kt * 32 + lq * 8];
            short8 b0 = *(const short8*)&wsp[P3_OFF + ((nt0 + 0) * 2 + kt) * 512 + l * 8];
            short8 b1 = *(const short8*)&wsp[P3_OFF + ((nt0 + 1) * 2 + kt) * 512 + l * 8];
            acc[0][0] = __builtin_amdgcn_mfma_f32_16x16x32_bf16(a0, b0, acc[0][0], 0, 0, 0);
            acc[0][1] = __builtin_amdgcn_mfma_f32_16x16x32_bf16(a0, b1, acc[0][1], 0, 0, 0);
            acc[1][0] = __builtin_amdgcn_mfma_f32_16x16x32_bf16(a1, b0, acc[1][0], 0, 0, 0);
            acc[1][1] = __builtin_amdgcn_mfma_f32_16x16x32_bf16(a1, b1, acc[1][1], 0, 0, 0);
        }
        #pragma unroll
        for (int m = 0; m < 2; ++m) {
            #pragma unroll
            for (int n = 0; n < 2; ++n) {
                int col = (nt0 + n) * 16 + lr;
                #pragma unroll
                for (int r = 0; r < 4; ++r) {
                    int row = m * 16 + lq * 4 + r;
                    float g  = acc[m][n][r];
                    float ex = __expf(-bf2f(Hb[row * LDA + col]));
                    Hb[row * LDA + col] = f2bf(fmaf(-g, ex, g));   // g*(1-exp(-h1))
                }
            }
        }
    }
    __syncthreads();

    // ========= G4: g1 = p1 @ P4;  p0 = g1 * (1-exp(-h0)) -> Ha IN PLACE =========
    {
        floatx4 acc[2][2];
        acc[0][0] = zero; acc[0][1] = zero; acc[1][0] = zero; acc[1][1] = zero;
        const int nt0 = ne * 2;
        #pragma unroll
        for (int kt = 0; kt < 8; ++kt) {
            short8 a0 = *(const short8*)&Hb[lr * LDA + kt * 32 + lq * 8];
            short8 a1 = *(const short8*)&Hb[(16 + lr) * LDA + kt * 32 + lq * 8];
            short8 b0 = *(const short8*)&wsp[P4_OFF + ((nt0 + 0) * 8 + kt) * 512 + l * 8];
            short8 b1 = *(const short8*)&wsp[P4_OFF + ((nt0 + 1) * 8 + kt) * 512 + l * 8];
            acc[0][0] = __builtin_amdgcn_mfma_f32_16x16x32_bf16(a0, b0, acc[0][0], 0, 0, 0);
            acc[0][1] = __builtin_amdgcn_mfma_f32_16x16x32_bf16(a0, b1, acc[0][1], 0, 0, 0);
            acc[1][0] = __builtin_amdgcn_mfma_f32_16x16x32_bf16(a1, b0, acc[1][0], 0, 0, 0);
            acc[1][1] = __builtin_amdgcn_mfma_f32_16x16x32_bf16(a1, b1, acc[1][1], 0, 0, 0);
        }
        #pragma unroll
        for (int m = 0; m < 2; ++m) {
            #pragma unroll
            for (int n = 0; n < 2; ++n) {
                int col = (nt0 + n) * 16 + lr;
                #pragma unroll
                for (int r = 0; r < 4; ++r) {
                    int row = m * 16 + lq * 4 + r;
                    float g  = acc[m][n][r];
                    float ex = __expf(-bf2f(Ha[row * LDA + col]));
                    Ha[row * LDA + col] = f2bf(fmaf(-g, ex, g));   // g*(1-exp(-h0))
                }
            }
        }
    }
    __syncthreads();

    // ====== G5: g0 = p0 @ P5;  div = sum(g0 * e);  out[:,64] = -div ======
    {
        floatx4 a0 = zero;
        #pragma unroll
        for (int kt = 0; kt < 8; ++kt) {
            short8 a = *(const short8*)&Ha[(mt * 16 + lr) * LDA + kt * 32 + lq * 8];
            short8 b = *(const short8*)&wsp[P5_OFF + (nq * 8 + kt) * 512 + l * 8];
            a0 = __builtin_amdgcn_mfma_f32_16x16x32_bf16(a, b, a0, 0, 0, 0);
        }
        int col = nq * 16 + lr;
        #pragma unroll
        for (int r = 0; r < 4; ++r) {
            int row = mt * 16 + lq * 4 + r;
            float v = a0[r] * e[(rowbase + row) * 64 + col];
            #pragma unroll
            for (int m = 1; m < 16; m <<= 1) v += __shfl_xor(v, m, 64);
            if (lr == 0) divp[nq][row] = v;
        }
    }
    __syncthreads();
    if (tid < RB)
        out[(rowbase + tid) * 65 + 64] =
            -(divp[0][tid] + divp[1][tid] + divp[2][tid] + divp[3][tid]);
}

// ---------------- fp32 vector fallback (used only if ws_size too small) ----------------
#define FNT 256
__global__ __launch_bounds__(FNT, 2)
void ode_fallback(const float* __restrict__ tptr,
                  const float* __restrict__ y, const float* __restrict__ e,
                  const float* __restrict__ W0, const float* __restrict__ b0,
                  const float* __restrict__ W1, const float* __restrict__ b1,
                  const float* __restrict__ W2, const float* __restrict__ b2,
                  float* __restrict__ out)
{
    __shared__ float H0[RB * 257];
    __shared__ float H1[RB * 257];
    __shared__ float ZE[RB * 68];

    const int tid = threadIdx.x;
    const int rowbase = blockIdx.x * RB;
    const float tval = tptr[0];
    const int cg = tid & 31, rg = tid >> 5;
    const int cg2 = tid & 15, rg2 = tid >> 4;

    {
        const int d = tid & 63, r0 = tid >> 6;
        for (int r = r0; r < RB; r += FNT / 64)
            ZE[r * 68 + d] = y[(rowbase + r) * 65 + d];
    }
    __syncthreads();

    float acc[4][8];
    float acc2[2][4];

    for (int i = 0; i < 4; ++i) for (int j = 0; j < 8; ++j) acc[i][j] = 0.0f;
    for (int s = 0; s < 64; ++s) {
        float b[8];
        for (int j = 0; j < 8; ++j) b[j] = W0[(cg * 8 + j) * 65 + 1 + s];
        float a[4];
        for (int i = 0; i < 4; ++i) a[i] = ZE[(rg * 4 + i) * 68 + s];
        for (int i = 0; i < 4; ++i) for (int j = 0; j < 8; ++j)
            acc[i][j] = fmaf(a[i], b[j], acc[i][j]);
    }
    for (int i = 0; i < 4; ++i) for (int j = 0; j < 8; ++j) {
        int n = cg * 8 + j;
        H0[(rg * 4 + i) * 257 + n] = softplus_fast(acc[i][j] + tval * W0[n * 65] + b0[n]);
    }
    __syncthreads();

    for (int idx = tid; idx < RB * 16; idx += FNT) {
        int r = idx >> 4, c = idx & 15;
        *(float4*)(&ZE[r * 68 + c * 4]) = *(const float4*)(e + (rowbase + r) * 64 + c * 4);
    }

    for (int i = 0; i < 4; ++i) for (int j = 0; j < 8; ++j) acc[i][j] = 0.0f;
    for (int s = 0; s < 256; ++s) {
        float b[8];
        for (int j = 0; j < 8; ++j) b[j] = W1[(cg * 8 + j) * 257 + 1 + s];
        float a[4];
        for (int i = 0; i < 4; ++i) a[i] = H0[(rg * 4 + i) * 257 + s];
        for (int i = 0; i < 4; ++i) for (int j = 0; j < 8; ++j)
            acc[i][j] = fmaf(a[i], b[j], acc[i][j]);
    }
    for (int i = 0; i < 4; ++i) for (int j = 0; j < 8; ++j) {
        int n = cg * 8 + j;
        H1[(rg * 4 + i) * 257 + n] = softplus_fast(acc[i][j] + tval * W1[n * 257] + b1[n]);
    }
    __syncthreads();

    for (int i = 0; i < 2; ++i) for (int j = 0; j < 4; ++j) acc2[i][j] = 0.0f;
    for (int s = 0; s < 256; ++s) {
        float b[4];
        for (int j = 0; j < 4; ++j) b[j] = W2[(cg2 * 4 + j) * 257 + 1 + s];
        float a[2];
        for (int i = 0; i < 2; ++i) a[i] = H1[(rg2 * 2 + i) * 257 + s];
        for (int i = 0; i < 2; ++i) for (int j = 0; j < 4; ++j)
            acc2[i][j] = fmaf(a[i], b[j], acc2[i][j]);
    }
    for (int i = 0; i < 2; ++i) for (int j = 0; j < 4; ++j) {
        int n = cg2 * 4 + j;
        out[(rowbase + rg2 * 2 + i) * 65 + n] = acc2[i][j] + tval * W2[n * 257] + b2[n];
    }
    __syncthreads();

    for (int i = 0; i < 4; ++i) for (int j = 0; j < 8; ++j) acc[i][j] = 0.0f;
    for (int s = 0; s < 64; ++s) {
        float b[8];
        for (int j = 0; j < 8; ++j) b[j] = W2[s * 257 + 1 + cg * 8 + j];
        float a[4];
        for (int i = 0; i < 4; ++i) a[i] = ZE[(rg * 4 + i) * 68 + s];
        for (int i = 0; i < 4; ++i) for (int j = 0; j < 8; ++j)
            acc[i][j] = fmaf(a[i], b[j], acc[i][j]);
    }
    for (int i = 0; i < 4; ++i) for (int j = 0; j < 8; ++j) {
        int r = rg * 4 + i, n = cg * 8 + j;
        float h = H1[r * 257 + n];
        H1[r * 257 + n] = acc[i][j] * (1.0f - __expf(-h));
    }
    __syncthreads();

    for (int i = 0; i < 4; ++i) for (int j = 0; j < 8; ++j) acc[i][j] = 0.0f;
    for (int s = 0; s < 256; ++s) {
        float b[8];
        for (int j = 0; j < 8; ++j) b[j] = W1[s * 257 + 1 + cg * 8 + j];
        float a[4];
        for (int i = 0; i < 4; ++i) a[i] = H1[(rg * 4 + i) * 257 + s];
        for (int i = 0; i < 4; ++i) for (int j = 0; j < 8; ++j)
            acc[i][j] = fmaf(a[i], b[j], acc[i][j]);
    }
    for (int i = 0; i < 4; ++i) for (int j = 0; j < 8; ++j) {
        int r = rg * 4 + i, n = cg * 8 + j;
        float h = H0[r * 257 + n];
        H0[r * 257 + n] = acc[i][j] * (1.0f - __expf(-h));
    }
    __syncthreads();

    for (int i = 0; i < 2; ++i) for (int j = 0; j < 4; ++j) acc2[i][j] = 0.0f;
    for (int s = 0; s < 256; ++s) {
        float b[4];
        for (int j = 0; j < 4; ++j) b[j] = W0[s * 65 + 1 + cg2 * 4 + j];
        float a[2];
        for (int i = 0; i < 2; ++i) a[i] = H0[(rg2 * 2 + i) * 257 + s];
        for (int i = 0; i < 2; ++i) for (int j = 0; j < 4; ++j)
            acc2[i][j] = fmaf(a[i], b[j], acc2[i][j]);
    }
    float pA = 0.0f, pB = 0.0f;
    for (int j = 0; j < 4; ++j) {
        int n = cg2 * 4 + j;
        pA = fmaf(acc2[0][j], ZE[(rg2 * 2 + 0) * 68 + n], pA);
        pB = fmaf(acc2[1][j], ZE[(rg2 * 2 + 1) * 68 + n], pB);
    }
    for (int off = 8; off > 0; off >>= 1) {
        pA += __shfl_down(pA, off, 16);
        pB += __shfl_down(pB, off, 16);
    }
    if (cg2 == 0) {
        out[(rowbase + rg2 * 2 + 0) * 65 + 64] = -pA;
        out[(rowbase + rg2 * 2 + 1) * 65 + 64] = -pB;
    }
}

extern "C" void kernel_launch(void* const* d_in, const int* in_sizes, int n_in,
                              void* d_out, int out_size, void* d_ws, size_t ws_size,
                              hipStream_t stream)
{
    const float* t  = (const float*)d_in[0];
    const float* y  = (const float*)d_in[1];
    const float* e  = (const float*)d_in[2];
    const float* W0 = (const float*)d_in[3];
    const float* b0 = (const float*)d_in[4];
    const float* W1 = (const float*)d_in[5];
    const float* b1 = (const float*)d_in[6];
    const float* W2 = (const float*)d_in[7];
    const float* b2 = (const float*)d_in[8];
    float* out = (float*)d_out;

    const int B = in_sizes[1] / 65;

    if (ws_size >= (size_t)WS_BYTES) {
        prep_pack<<<(PACK_ELEMS + 576 + 255) / 256, 256, 0, stream>>>(
            t, W0, b0, W1, b1, W2, b2, (short*)d_ws);
        ode_mfma<<<B / RB, NT, 0, stream>>>(y, e, (const short*)d_ws, out);
    } else {
        ode_fallback<<<B / RB, FNT, 0, stream>>>(t, y, e, W0, b0, W1, b1, W2, b2, out);
    }
}

// Round 6
// 330.064 us; speedup vs baseline: 1.0346x; 1.0346x over previous
//
#include <hip/hip_runtime.h>
#include <math.h>

// FFJORD ODE func: 3-layer MLP fwd + VJP + Hutchinson divergence.
// B=262144 rows, D=64, H=256. bf16 MFMA (16x16x32), fp32 accumulate.
// R6: SWAPPED operands (A=weight frag, B=activation frag) -> accumulator is
//     [nout][batch]; each lane's 4 acc values are 4 consecutive nout at fixed
//     batch row -> all epilogue LDS traffic becomes b64 (was scattered b16),
//     bias fold becomes one float4 C-init, staging packs to b64 writes.
//     Weight frag packing is role-agnostic (A/B layouts are transposes).
//
// ws layout (UNCHANGED from R5):
//   bf16 packed W-fragments (frag = 512 bf16, frag_id = t*KT+kt):
//     P0 @ elem 0      : fwd L0  W0[n][1+s]  (KT=2,  32 frags)
//     P1 @ elem 16384  : fwd L1  W1[n][1+s]  (KT=8, 128 frags)
//     P2 @ elem 81920  : fwd L2  W2[n][1+s]  (KT=8,  32 frags)
//     P3 @ elem 98304  : bwd g2  W2[s][1+n]  (KT=2,  32 frags)
//     P4 @ elem 114688 : bwd g1  W1[s][1+n]  (KT=8, 128 frags)
//     P5 @ elem 180224 : bwd g0  W0[s][1+n]  (KT=8,  32 frags)
//   fp32 cst @ byte 393216: cst0[256], cst1[256], cst2[64] = t*W[:,0]+b

typedef __attribute__((ext_vector_type(8))) short short8;
typedef __attribute__((ext_vector_type(4))) short sh4;
typedef __attribute__((ext_vector_type(4))) float floatx4;

#define NT 512    // 8 waves
#define RB 32
#define LDA 264   // bf16 row stride (528 B)
#define LDZ 72

#define P0_OFF 0
#define P1_OFF 16384
#define P2_OFF 81920
#define P3_OFF 98304
#define P4_OFF 114688
#define P5_OFF 180224
#define PACK_ELEMS 196608
#define CST_BYTE_OFF (PACK_ELEMS * 2)
#define WS_BYTES (CST_BYTE_OFF + 576 * 4)

static __device__ __forceinline__ short f2bf(float f) {
    union { float f; unsigned u; } v; v.f = f;
    unsigned r = v.u + 0x7FFFu + ((v.u >> 16) & 1u);   // RNE
    return (short)(r >> 16);
}
static __device__ __forceinline__ float bf2f(short h) {
    union { unsigned u; float f; } v; v.u = ((unsigned)(unsigned short)h) << 16;
    return v.f;
}
// Fast softplus: native v_exp_f32/v_log_f32; error ~2^-24 abs, invisible at bf16.
static __device__ __forceinline__ float softplus_fast(float x) {
    float u = __expf(-fabsf(x));
    return fmaxf(x, 0.0f) + __logf(1.0f + u);
}

__global__ void prep_pack(const float* __restrict__ t,
                          const float* __restrict__ W0, const float* __restrict__ b0,
                          const float* __restrict__ W1, const float* __restrict__ b1,
                          const float* __restrict__ W2, const float* __restrict__ b2,
                          short* __restrict__ wsp)
{
    int i = blockIdx.x * blockDim.x + threadIdx.x;
    if (i < PACK_ELEMS) {
        int jin, ld, mode, kt, nt; const float* src;
        if      (i < P1_OFF) { jin = i - P0_OFF; src = W0; ld = 65;  mode = 0;
                               int f = jin >> 9; kt = f & 1; nt = f >> 1; }
        else if (i < P2_OFF) { jin = i - P1_OFF; src = W1; ld = 257; mode = 0;
                               int f = jin >> 9; kt = f & 7; nt = f >> 3; }
        else if (i < P3_OFF) { jin = i - P2_OFF; src = W2; ld = 257; mode = 0;
                               int f = jin >> 9; kt = f & 7; nt = f >> 3; }
        else if (i < P4_OFF) { jin = i - P3_OFF; src = W2; ld = 257; mode = 1;
                               int f = jin >> 9; kt = f & 1; nt = f >> 1; }
        else if (i < P5_OFF) { jin = i - P4_OFF; src = W1; ld = 257; mode = 1;
                               int f = jin >> 9; kt = f & 7; nt = f >> 3; }
        else                 { jin = i - P5_OFF; src = W0; ld = 65;  mode = 1;
                               int f = jin >> 9; kt = f & 7; nt = f >> 3; }
        int r = jin & 511;
        int lane = r >> 3, jj = r & 7;
        int k = kt * 32 + (lane >> 4) * 8 + jj;
        int n = nt * 16 + (lane & 15);
        float v = (mode == 0) ? src[n * ld + 1 + k] : src[k * ld + 1 + n];
        wsp[i] = f2bf(v);
    } else if (i < PACK_ELEMS + 576) {
        int ci = i - PACK_ELEMS;
        float tv = t[0];
        float* cst = (float*)((char*)wsp + CST_BYTE_OFF);
        float v;
        if (ci < 256)      v = tv * W0[ci * 65] + b0[ci];
        else if (ci < 512) { int n = ci - 256; v = tv * W1[n * 257] + b1[n]; }
        else               { int n = ci - 512; v = tv * W2[n * 257] + b2[n]; }
        cst[ci] = v;
    }
}

__global__ __launch_bounds__(NT, 8)   // 8 waves/EU -> 4 blocks/CU, VGPR cap 64
void ode_mfma(const float* __restrict__ y, const float* __restrict__ e,
              const short* __restrict__ wsp, float* __restrict__ out)
{
    __shared__ __align__(16) short Az[RB * LDZ];   // z bf16, then e bf16 (after G0)
    __shared__ __align__(16) short Ha[RB * LDA];   // h0, then p0 (in place)
    __shared__ __align__(16) short Hb[RB * LDA];   // h1, then p1 (in place)
    __shared__ float divp[4][RB];
    // LDS total: 38912 B -> 4 blocks/CU

    const int tid = threadIdx.x;
    const int rowbase = blockIdx.x * RB;
    const int w = tid >> 6, l = tid & 63;
    const int lr = l & 15, lq = l >> 4;
    // Big GEMMs (256 nout): wave w owns m-tiles (nout) {2w, 2w+1}, n-tiles (batch) {0,1}.
    // Small GEMMs (64 nout): wave = (mt2 = w&3 nout-tile, n2 = w>>2 batch-tile).
    const int mt2 = w & 3, n2 = w >> 2;
    const float* cst = (const float*)((const char*)wsp + CST_BYTE_OFF);

    // ---- stage z = y[:, :64] (4 elems/thread -> 1 b64 write) ----
    {
        int r = tid >> 4, c4 = (tid & 15) * 4;
        const float* yp = y + (rowbase + r) * 65 + c4;
        sh4 s;
        s[0] = f2bf(yp[0]); s[1] = f2bf(yp[1]); s[2] = f2bf(yp[2]); s[3] = f2bf(yp[3]);
        *(sh4*)&Az[r * LDZ + c4] = s;
    }
    __syncthreads();

    const floatx4 zero = {0.f, 0.f, 0.f, 0.f};

    // ============ G0: h0^T = W0frag @ z^T + cst0;  store softplus -> Ha ============
    {
        floatx4 acc[2][2];   // [mi][n]  (mi: nout tile 2w+mi, n: batch tile)
        #pragma unroll
        for (int mi = 0; mi < 2; ++mi) {
            floatx4 c = *(const floatx4*)&cst[(2 * w + mi) * 16 + lq * 4];
            acc[mi][0] = c; acc[mi][1] = c;
        }
        #pragma unroll
        for (int kt = 0; kt < 2; ++kt) {
            short8 wa0 = *(const short8*)&wsp[P0_OFF + ((2 * w + 0) * 2 + kt) * 512 + l * 8];
            short8 wa1 = *(const short8*)&wsp[P0_OFF + ((2 * w + 1) * 2 + kt) * 512 + l * 8];
            short8 hb0 = *(const short8*)&Az[lr * LDZ + kt * 32 + lq * 8];
            short8 hb1 = *(const short8*)&Az[(16 + lr) * LDZ + kt * 32 + lq * 8];
            acc[0][0] = __builtin_amdgcn_mfma_f32_16x16x32_bf16(wa0, hb0, acc[0][0], 0, 0, 0);
            acc[0][1] = __builtin_amdgcn_mfma_f32_16x16x32_bf16(wa0, hb1, acc[0][1], 0, 0, 0);
            acc[1][0] = __builtin_amdgcn_mfma_f32_16x16x32_bf16(wa1, hb0, acc[1][0], 0, 0, 0);
            acc[1][1] = __builtin_amdgcn_mfma_f32_16x16x32_bf16(wa1, hb1, acc[1][1], 0, 0, 0);
        }
        #pragma unroll
        for (int mi = 0; mi < 2; ++mi) {
            #pragma unroll
            for (int n = 0; n < 2; ++n) {
                int row = n * 16 + lr;                       // batch
                int col = (2 * w + mi) * 16 + lq * 4;        // nout (4 consecutive)
                sh4 s;
                #pragma unroll
                for (int r = 0; r < 4; ++r) s[r] = f2bf(softplus_fast(acc[mi][n][r]));
                *(sh4*)&Ha[row * LDA + col] = s;
            }
        }
    }
    __syncthreads();

    // ---- stage e -> Az (z dead; e consumed from G3 on; G1/G2 barriers cover) ----
    {
        int r = tid >> 4, c4 = (tid & 15) * 4;
        float4 ev = *(const float4*)(e + (rowbase + r) * 64 + c4);
        sh4 s;
        s[0] = f2bf(ev.x); s[1] = f2bf(ev.y); s[2] = f2bf(ev.z); s[3] = f2bf(ev.w);
        *(sh4*)&Az[r * LDZ + c4] = s;
    }

    // ============ G1: h1^T = W1frag @ h0^T + cst1 -> Hb ============
    {
        floatx4 acc[2][2];
        #pragma unroll
        for (int mi = 0; mi < 2; ++mi) {
            floatx4 c = *(const floatx4*)&cst[256 + (2 * w + mi) * 16 + lq * 4];
            acc[mi][0] = c; acc[mi][1] = c;
        }
        #pragma unroll
        for (int kt = 0; kt < 8; ++kt) {
            short8 wa0 = *(const short8*)&wsp[P1_OFF + ((2 * w + 0) * 8 + kt) * 512 + l * 8];
            short8 wa1 = *(const short8*)&wsp[P1_OFF + ((2 * w + 1) * 8 + kt) * 512 + l * 8];
            short8 hb0 = *(const short8*)&Ha[lr * LDA + kt * 32 + lq * 8];
            short8 hb1 = *(const short8*)&Ha[(16 + lr) * LDA + kt * 32 + lq * 8];
            acc[0][0] = __builtin_amdgcn_mfma_f32_16x16x32_bf16(wa0, hb0, acc[0][0], 0, 0, 0);
            acc[0][1] = __builtin_amdgcn_mfma_f32_16x16x32_bf16(wa0, hb1, acc[0][1], 0, 0, 0);
            acc[1][0] = __builtin_amdgcn_mfma_f32_16x16x32_bf16(wa1, hb0, acc[1][0], 0, 0, 0);
            acc[1][1] = __builtin_amdgcn_mfma_f32_16x16x32_bf16(wa1, hb1, acc[1][1], 0, 0, 0);
        }
        #pragma unroll
        for (int mi = 0; mi < 2; ++mi) {
            #pragma unroll
            for (int n = 0; n < 2; ++n) {
                int row = n * 16 + lr;
                int col = (2 * w + mi) * 16 + lq * 4;
                sh4 s;
                #pragma unroll
                for (int r = 0; r < 4; ++r) s[r] = f2bf(softplus_fast(acc[mi][n][r]));
                *(sh4*)&Hb[row * LDA + col] = s;
            }
        }
    }
    __syncthreads();

    // ============ G2: dx^T = W2frag @ h1^T + cst2 -> out[:, :64] ============
    {
        floatx4 a0 = *(const floatx4*)&cst[512 + mt2 * 16 + lq * 4];
        #pragma unroll
        for (int kt = 0; kt < 8; ++kt) {
            short8 wa = *(const short8*)&wsp[P2_OFF + (mt2 * 8 + kt) * 512 + l * 8];
            short8 hb = *(const short8*)&Hb[(n2 * 16 + lr) * LDA + kt * 32 + lq * 8];
            a0 = __builtin_amdgcn_mfma_f32_16x16x32_bf16(wa, hb, a0, 0, 0, 0);
        }
        int batch = n2 * 16 + lr;
        int col = mt2 * 16 + lq * 4;
        float* op = out + (rowbase + batch) * 65 + col;
        op[0] = a0[0]; op[1] = a0[1]; op[2] = a0[2]; op[3] = a0[3];
    }
    __syncthreads();   // all Hb (h1) reads done before G3 overwrites Hb

    // ==== G3: g2^T = W2Tfrag @ e^T;  p1 = g2*(1-exp(-h1)) -> Hb IN PLACE ====
    {
        floatx4 acc[2][2];
        acc[0][0] = zero; acc[0][1] = zero; acc[1][0] = zero; acc[1][1] = zero;
        #pragma unroll
        for (int kt = 0; kt < 2; ++kt) {
            short8 wa0 = *(const short8*)&wsp[P3_OFF + ((2 * w + 0) * 2 + kt) * 512 + l * 8];
            short8 wa1 = *(const short8*)&wsp[P3_OFF + ((2 * w + 1) * 2 + kt) * 512 + l * 8];
            short8 eb0 = *(const short8*)&Az[lr * LDZ + kt * 32 + lq * 8];
            short8 eb1 = *(const short8*)&Az[(16 + lr) * LDZ + kt * 32 + lq * 8];
            acc[0][0] = __builtin_amdgcn_mfma_f32_16x16x32_bf16(wa0, eb0, acc[0][0], 0, 0, 0);
            acc[0][1] = __builtin_amdgcn_mfma_f32_16x16x32_bf16(wa0, eb1, acc[0][1], 0, 0, 0);
            acc[1][0] = __builtin_amdgcn_mfma_f32_16x16x32_bf16(wa1, eb0, acc[1][0], 0, 0, 0);
            acc[1][1] = __builtin_amdgcn_mfma_f32_16x16x32_bf16(wa1, eb1, acc[1][1], 0, 0, 0);
        }
        #pragma unroll
        for (int mi = 0; mi < 2; ++mi) {
            #pragma unroll
            for (int n = 0; n < 2; ++n) {
                int row = n * 16 + lr;
                int col = (2 * w + mi) * 16 + lq * 4;
                sh4 old = *(const sh4*)&Hb[row * LDA + col];
                sh4 s;
                #pragma unroll
                for (int r = 0; r < 4; ++r) {
                    float g  = acc[mi][n][r];
                    float ex = __expf(-bf2f(old[r]));
                    s[r] = f2bf(fmaf(-g, ex, g));          // g*(1-exp(-h1))
                }
                *(sh4*)&Hb[row * LDA + col] = s;
            }
        }
    }
    __syncthreads();

    // ==== G4: g1^T = W1Tfrag @ p1^T;  p0 = g1*(1-exp(-h0)) -> Ha IN PLACE ====
    {
        floatx4 acc[2][2];
        acc[0][0] = zero; acc[0][1] = zero; acc[1][0] = zero; acc[1][1] = zero;
        #pragma unroll
        for (int kt = 0; kt < 8; ++kt) {
            short8 wa0 = *(const short8*)&wsp[P4_OFF + ((2 * w + 0) * 8 + kt) * 512 + l * 8];
            short8 wa1 = *(const short8*)&wsp[P4_OFF + ((2 * w + 1) * 8 + kt) * 512 + l * 8];
            short8 pb0 = *(const short8*)&Hb[lr * LDA + kt * 32 + lq * 8];
            short8 pb1 = *(const short8*)&Hb[(16 + lr) * LDA + kt * 32 + lq * 8];
            acc[0][0] = __builtin_amdgcn_mfma_f32_16x16x32_bf16(wa0, pb0, acc[0][0], 0, 0, 0);
            acc[0][1] = __builtin_amdgcn_mfma_f32_16x16x32_bf16(wa0, pb1, acc[0][1], 0, 0, 0);
            acc[1][0] = __builtin_amdgcn_mfma_f32_16x16x32_bf16(wa1, pb0, acc[1][0], 0, 0, 0);
            acc[1][1] = __builtin_amdgcn_mfma_f32_16x16x32_bf16(wa1, pb1, acc[1][1], 0, 0, 0);
        }
        #pragma unroll
        for (int mi = 0; mi < 2; ++mi) {
            #pragma unroll
            for (int n = 0; n < 2; ++n) {
                int row = n * 16 + lr;
                int col = (2 * w + mi) * 16 + lq * 4;
                sh4 old = *(const sh4*)&Ha[row * LDA + col];
                sh4 s;
                #pragma unroll
                for (int r = 0; r < 4; ++r) {
                    float g  = acc[mi][n][r];
                    float ex = __expf(-bf2f(old[r]));
                    s[r] = f2bf(fmaf(-g, ex, g));          // g*(1-exp(-h0))
                }
                *(sh4*)&Ha[row * LDA + col] = s;
            }
        }
    }
    __syncthreads();

    // ==== G5: g0^T = W0Tfrag @ p0^T;  div = sum(g0*e);  out[:,64] = -div ====
    {
        floatx4 a0 = zero;
        #pragma unroll
        for (int kt = 0; kt < 8; ++kt) {
            short8 wa = *(const short8*)&wsp[P5_OFF + (mt2 * 8 + kt) * 512 + l * 8];
            short8 pb = *(const short8*)&Ha[(n2 * 16 + lr) * LDA + kt * 32 + lq * 8];
            a0 = __builtin_amdgcn_mfma_f32_16x16x32_bf16(wa, pb, a0, 0, 0, 0);
        }
        int batch = n2 * 16 + lr;
        float4 ev = *(const float4*)(e + (rowbase + batch) * 64 + mt2 * 16 + lq * 4);
        float v = a0[0] * ev.x + a0[1] * ev.y + a0[2] * ev.z + a0[3] * ev.w;
        v += __shfl_xor(v, 16, 64);
        v += __shfl_xor(v, 32, 64);
        if (lq == 0) divp[mt2][batch] = v;
    }
    __syncthreads();
    if (tid < RB)
        out[(rowbase + tid) * 65 + 64] =
            -(divp[0][tid] + divp[1][tid] + divp[2][tid] + divp[3][tid]);
}

// ---------------- fp32 vector fallback (used only if ws_size too small) ----------------
#define FNT 256
__global__ __launch_bounds__(FNT, 2)
void ode_fallback(const float* __restrict__ tptr,
                  const float* __restrict__ y, const float* __restrict__ e,
                  const float* __restrict__ W0, const float* __restrict__ b0,
                  const float* __restrict__ W1, const float* __restrict__ b1,
                  const float* __restrict__ W2, const float* __restrict__ b2,
                  float* __restrict__ out)
{
    __shared__ float H0[RB * 257];
    __shared__ float H1[RB * 257];
    __shared__ float ZE[RB * 68];

    const int tid = threadIdx.x;
    const int rowbase = blockIdx.x * RB;
    const float tval = tptr[0];
    const int cg = tid & 31, rg = tid >> 5;
    const int cg2 = tid & 15, rg2 = tid >> 4;

    {
        const int d = tid & 63, r0 = tid >> 6;
        for (int r = r0; r < RB; r += FNT / 64)
            ZE[r * 68 + d] = y[(rowbase + r) * 65 + d];
    }
    __syncthreads();

    float acc[4][8];
    float acc2[2][4];

    for (int i = 0; i < 4; ++i) for (int j = 0; j < 8; ++j) acc[i][j] = 0.0f;
    for (int s = 0; s < 64; ++s) {
        float b[8];
        for (int j = 0; j < 8; ++j) b[j] = W0[(cg * 8 + j) * 65 + 1 + s];
        float a[4];
        for (int i = 0; i < 4; ++i) a[i] = ZE[(rg * 4 + i) * 68 + s];
        for (int i = 0; i < 4; ++i) for (int j = 0; j < 8; ++j)
            acc[i][j] = fmaf(a[i], b[j], acc[i][j]);
    }
    for (int i = 0; i < 4; ++i) for (int j = 0; j < 8; ++j) {
        int n = cg * 8 + j;
        H0[(rg * 4 + i) * 257 + n] = softplus_fast(acc[i][j] + tval * W0[n * 65] + b0[n]);
    }
    __syncthreads();

    for (int idx = tid; idx < RB * 16; idx += FNT) {
        int r = idx >> 4, c = idx & 15;
        *(float4*)(&ZE[r * 68 + c * 4]) = *(const float4*)(e + (rowbase + r) * 64 + c * 4);
    }

    for (int i = 0; i < 4; ++i) for (int j = 0; j < 8; ++j) acc[i][j] = 0.0f;
    for (int s = 0; s < 256; ++s) {
        float b[8];
        for (int j = 0; j < 8; ++j) b[j] = W1[(cg * 8 + j) * 257 + 1 + s];
        float a[4];
        for (int i = 0; i < 4; ++i) a[i] = H0[(rg * 4 + i) * 257 + s];
        for (int i = 0; i < 4; ++i) for (int j = 0; j < 8; ++j)
            acc[i][j] = fmaf(a[i], b[j], acc[i][j]);
    }
    for (int i = 0; i < 4; ++i) for (int j = 0; j < 8; ++j) {
        int n = cg * 8 + j;
        H1[(rg * 4 + i) * 257 + n] = softplus_fast(acc[i][j] + tval * W1[n * 257] + b1[n]);
    }
    __syncthreads();

    for (int i = 0; i < 2; ++i) for (int j = 0; j < 4; ++j) acc2[i][j] = 0.0f;
    for (int s = 0; s < 256; ++s) {
        float b[4];
        for (int j = 0; j < 4; ++j) b[j] = W2[(cg2 * 4 + j) * 257 + 1 + s];
        float a[2];
        for (int i = 0; i < 2; ++i) a[i] = H1[(rg2 * 2 + i) * 257 + s];
        for (int i = 0; i < 2; ++i) for (int j = 0; j < 4; ++j)
            acc2[i][j] = fmaf(a[i], b[j], acc2[i][j]);
    }
    for (int i = 0; i < 2; ++i) for (int j = 0; j < 4; ++j) {
        int n = cg2 * 4 + j;
        out[(rowbase + rg2 * 2 + i) * 65 + n] = acc2[i][j] + tval * W2[n * 257] + b2[n];
    }
    __syncthreads();

    for (int i = 0; i < 4; ++i) for (int j = 0; j < 8; ++j) acc[i][j] = 0.0f;
    for (int s = 0; s < 64; ++s) {
        float b[8];
        for (int j = 0; j < 8; ++j) b[j] = W2[s * 257 + 1 + cg * 8 + j];
        float a[4];
        for (int i = 0; i < 4; ++i) a[i] = ZE[(rg * 4 + i) * 68 + s];
        for (int i = 0; i < 4; ++i) for (int j = 0; j < 8; ++j)
            acc[i][j] = fmaf(a[i], b[j], acc[i][j]);
    }
    for (int i = 0; i < 4; ++i) for (int j = 0; j < 8; ++j) {
        int r = rg * 4 + i, n = cg * 8 + j;
        float h = H1[r * 257 + n];
        H1[r * 257 + n] = acc[i][j] * (1.0f - __expf(-h));
    }
    __syncthreads();

    for (int i = 0; i < 4; ++i) for (int j = 0; j < 8; ++j) acc[i][j] = 0.0f;
    for (int s = 0; s < 256; ++s) {
        float b[8];
        for (int j = 0; j < 8; ++j) b[j] = W1[s * 257 + 1 + cg * 8 + j];
        float a[4];
        for (int i = 0; i < 4; ++i) a[i] = H1[(rg * 4 + i) * 257 + s];
        for (int i = 0; i < 4; ++i) for (int j = 0; j < 8; ++j)
            acc[i][j] = fmaf(a[i], b[j], acc[i][j]);
    }
    for (int i = 0; i < 4; ++i) for (int j = 0; j < 8; ++j) {
        int r = rg * 4 + i, n = cg * 8 + j;
        float h = H0[r * 257 + n];
        H0[r * 257 + n] = acc[i][j] * (1.0f - __expf(-h));
    }
    __syncthreads();

    for (int i = 0; i < 2; ++i) for (int j = 0; j < 4; ++j) acc2[i][j] = 0.0f;
    for (int s = 0; s < 256; ++s) {
        float b[4];
        for (int j = 0; j < 4; ++j) b[j] = W0[s * 65 + 1 + cg2 * 4 + j];
        float a[2];
        for (int i = 0; i < 2; ++i) a[i] = H0[(rg2 * 2 + i) * 257 + s];
        for (int i = 0; i < 2; ++i) for (int j = 0; j < 4; ++j)
            acc2[i][j] = fmaf(a[i], b[j], acc2[i][j]);
    }
    float pA = 0.0f, pB = 0.0f;
    for (int j = 0; j < 4; ++j) {
        int n = cg2 * 4 + j;
        pA = fmaf(acc2[0][j], ZE[(rg2 * 2 + 0) * 68 + n], pA);
        pB = fmaf(acc2[1][j], ZE[(rg2 * 2 + 1) * 68 + n], pB);
    }
    for (int off = 8; off > 0; off >>= 1) {
        pA += __shfl_down(pA, off, 16);
        pB += __shfl_down(pB, off, 16);
    }
    if (cg2 == 0) {
        out[(rowbase + rg2 * 2 + 0) * 65 + 64] = -pA;
        out[(rowbase + rg2 * 2 + 1) * 65 + 64] = -pB;
    }
}

extern "C" void kernel_launch(void* const* d_in, const int* in_sizes, int n_in,
                              void* d_out, int out_size, void* d_ws, size_t ws_size,
                              hipStream_t stream)
{
    const float* t  = (const float*)d_in[0];
    const float* y  = (const float*)d_in[1];
    const float* e  = (const float*)d_in[2];
    const float* W0 = (const float*)d_in[3];
    const float* b0 = (const float*)d_in[4];
    const float* W1 = (const float*)d_in[5];
    const float* b1 = (const float*)d_in[6];
    const float* W2 = (const float*)d_in[7];
    const float* b2 = (const float*)d_in[8];
    float* out = (float*)d_out;

    const int B = in_sizes[1] / 65;

    if (ws_size >= (size_t)WS_BYTES) {
        prep_pack<<<(PACK_ELEMS + 576 + 255) / 256, 256, 0, stream>>>(
            t, W0, b0, W1, b1, W2, b2, (short*)d_ws);
        ode_mfma<<<B / RB, NT, 0, stream>>>(y, e, (const short*)d_ws, out);
    } else {
        ode_fallback<<<B / RB, FNT, 0, stream>>>(t, y, e, W0, b0, W1, b1, W2, b2, out);
    }
}

// Round 7
// 327.938 us; speedup vs baseline: 1.0414x; 1.0065x over previous
//
#include <hip/hip_runtime.h>
#include <math.h>

// FFJORD ODE func: 3-layer MLP fwd + VJP + Hutchinson divergence.
// B=262144 rows, D=64, H=256. bf16 MFMA (16x16x32), fp32 accumulate.
// R7: cheap bf16 packing (round-half-up hi-half merge, ~1.5 VALU op/value vs
//     ~4 for RNE f2bf) on all LDS stores + uint2 unpack on RMW reads; hoisted
//     fragment base pointers. Structure/layout unchanged from R6.
//
// ws layout (UNCHANGED):
//   bf16 packed W-fragments (frag = 512 bf16, frag_id = t*KT+kt):
//     P0 @ elem 0      : fwd L0  W0[n][1+s]  (KT=2,  32 frags)
//     P1 @ elem 16384  : fwd L1  W1[n][1+s]  (KT=8, 128 frags)
//     P2 @ elem 81920  : fwd L2  W2[n][1+s]  (KT=8,  32 frags)
//     P3 @ elem 98304  : bwd g2  W2[s][1+n]  (KT=2,  32 frags)
//     P4 @ elem 114688 : bwd g1  W1[s][1+n]  (KT=8, 128 frags)
//     P5 @ elem 180224 : bwd g0  W0[s][1+n]  (KT=8,  32 frags)
//   fp32 cst @ byte 393216: cst0[256], cst1[256], cst2[64] = t*W[:,0]+b

typedef __attribute__((ext_vector_type(8))) short short8;
typedef __attribute__((ext_vector_type(4))) float floatx4;

#define NT 512    // 8 waves
#define RB 32
#define LDA 264   // bf16 row stride (528 B)
#define LDZ 72

#define P0_OFF 0
#define P1_OFF 16384
#define P2_OFF 81920
#define P3_OFF 98304
#define P4_OFF 114688
#define P5_OFF 180224
#define PACK_ELEMS 196608
#define CST_BYTE_OFF (PACK_ELEMS * 2)
#define WS_BYTES (CST_BYTE_OFF + 576 * 4)

static __device__ __forceinline__ short f2bf(float f) {
    union { float f; unsigned u; } v; v.f = f;
    unsigned r = v.u + 0x7FFFu + ((v.u >> 16) & 1u);   // RNE (prep only)
    return (short)(r >> 16);
}
// pack two floats -> one dword of 2 bf16 (lo, hi), round-half-up (<=1/2 ulp).
static __device__ __forceinline__ unsigned pk2(float lo, float hi) {
    union { float f; unsigned u; } a, b; a.f = lo; b.f = hi;
    return ((b.u + 0x8000u) & 0xFFFF0000u) | ((a.u + 0x8000u) >> 16);
}
static __device__ __forceinline__ float lo2f(unsigned u) {
    union { unsigned u; float f; } v; v.u = u << 16; return v.f;
}
static __device__ __forceinline__ float hi2f(unsigned u) {
    union { unsigned u; float f; } v; v.u = u & 0xFFFF0000u; return v.f;
}
// Fast softplus: native v_exp_f32/v_log_f32; error ~2^-24 abs, invisible at bf16.
static __device__ __forceinline__ float softplus_fast(float x) {
    float u = __expf(-fabsf(x));
    return fmaxf(x, 0.0f) + __logf(1.0f + u);
}

__global__ void prep_pack(const float* __restrict__ t,
                          const float* __restrict__ W0, const float* __restrict__ b0,
                          const float* __restrict__ W1, const float* __restrict__ b1,
                          const float* __restrict__ W2, const float* __restrict__ b2,
                          short* __restrict__ wsp)
{
    int i = blockIdx.x * blockDim.x + threadIdx.x;
    if (i < PACK_ELEMS) {
        int jin, ld, mode, kt, nt; const float* src;
        if      (i < P1_OFF) { jin = i - P0_OFF; src = W0; ld = 65;  mode = 0;
                               int f = jin >> 9; kt = f & 1; nt = f >> 1; }
        else if (i < P2_OFF) { jin = i - P1_OFF; src = W1; ld = 257; mode = 0;
                               int f = jin >> 9; kt = f & 7; nt = f >> 3; }
        else if (i < P3_OFF) { jin = i - P2_OFF; src = W2; ld = 257; mode = 0;
                               int f = jin >> 9; kt = f & 7; nt = f >> 3; }
        else if (i < P4_OFF) { jin = i - P3_OFF; src = W2; ld = 257; mode = 1;
                               int f = jin >> 9; kt = f & 1; nt = f >> 1; }
        else if (i < P5_OFF) { jin = i - P4_OFF; src = W1; ld = 257; mode = 1;
                               int f = jin >> 9; kt = f & 7; nt = f >> 3; }
        else                 { jin = i - P5_OFF; src = W0; ld = 65;  mode = 1;
                               int f = jin >> 9; kt = f & 7; nt = f >> 3; }
        int r = jin & 511;
        int lane = r >> 3, jj = r & 7;
        int k = kt * 32 + (lane >> 4) * 8 + jj;
        int n = nt * 16 + (lane & 15);
        float v = (mode == 0) ? src[n * ld + 1 + k] : src[k * ld + 1 + n];
        wsp[i] = f2bf(v);
    } else if (i < PACK_ELEMS + 576) {
        int ci = i - PACK_ELEMS;
        float tv = t[0];
        float* cst = (float*)((char*)wsp + CST_BYTE_OFF);
        float v;
        if (ci < 256)      v = tv * W0[ci * 65] + b0[ci];
        else if (ci < 512) { int n = ci - 256; v = tv * W1[n * 257] + b1[n]; }
        else               { int n = ci - 512; v = tv * W2[n * 257] + b2[n]; }
        cst[ci] = v;
    }
}

__global__ __launch_bounds__(NT, 8)   // 8 waves/EU -> 4 blocks/CU, VGPR cap 64
void ode_mfma(const float* __restrict__ y, const float* __restrict__ e,
              const short* __restrict__ wsp, float* __restrict__ out)
{
    __shared__ __align__(16) short Az[RB * LDZ];   // z bf16, then e bf16 (after G0)
    __shared__ __align__(16) short Ha[RB * LDA];   // h0, then p0 (in place)
    __shared__ __align__(16) short Hb[RB * LDA];   // h1, then p1 (in place)
    __shared__ float divp[4][RB];
    // LDS total: 38912 B -> 4 blocks/CU

    const int tid = threadIdx.x;
    const int rowbase = blockIdx.x * RB;
    const int w = tid >> 6, l = tid & 63;
    const int lr = l & 15, lq = l >> 4;
    // Big GEMMs (256 nout): wave w owns nout-tiles {2w,2w+1}, batch-tiles {0,1}.
    // Small GEMMs (64 nout): wave = (mt2 = w&3 nout-tile, n2 = w>>2 batch-tile).
    const int mt2 = w & 3, n2 = w >> 2;
    const float* cst = (const float*)((const char*)wsp + CST_BYTE_OFF);

    // hoisted per-wave fragment base pointers (imm-offset friendly)
    const short* pw0 = wsp + P0_OFF + (4 * w) * 512 + l * 8;      // frags (2w+mi)*2+kt
    const short* pw1 = wsp + P1_OFF + (16 * w) * 512 + l * 8;     // frags (2w+mi)*8+kt
    const short* pw2 = wsp + P2_OFF + (mt2 * 8) * 512 + l * 8;
    const short* pw3 = wsp + P3_OFF + (4 * w) * 512 + l * 8;
    const short* pw4 = wsp + P4_OFF + (16 * w) * 512 + l * 8;
    const short* pw5 = wsp + P5_OFF + (mt2 * 8) * 512 + l * 8;

    // ---- stage z = y[:, :64] (4 elems/thread -> 1 b64 write) ----
    {
        int r = tid >> 4, c4 = (tid & 15) * 4;
        const float* yp = y + (rowbase + r) * 65 + c4;
        uint2 s; s.x = pk2(yp[0], yp[1]); s.y = pk2(yp[2], yp[3]);
        *(uint2*)&Az[r * LDZ + c4] = s;
    }
    __syncthreads();

    const floatx4 zero = {0.f, 0.f, 0.f, 0.f};

    // ============ G0: h0^T = W0frag @ z^T + cst0;  softplus -> Ha ============
    {
        floatx4 acc[2][2];   // [mi][n]
        #pragma unroll
        for (int mi = 0; mi < 2; ++mi) {
            floatx4 c = *(const floatx4*)&cst[(2 * w + mi) * 16 + lq * 4];
            acc[mi][0] = c; acc[mi][1] = c;
        }
        #pragma unroll
        for (int kt = 0; kt < 2; ++kt) {
            short8 wa0 = *(const short8*)(pw0 + (kt)     * 512);
            short8 wa1 = *(const short8*)(pw0 + (2 + kt) * 512);
            short8 hb0 = *(const short8*)&Az[lr * LDZ + kt * 32 + lq * 8];
            short8 hb1 = *(const short8*)&Az[(16 + lr) * LDZ + kt * 32 + lq * 8];
            acc[0][0] = __builtin_amdgcn_mfma_f32_16x16x32_bf16(wa0, hb0, acc[0][0], 0, 0, 0);
            acc[0][1] = __builtin_amdgcn_mfma_f32_16x16x32_bf16(wa0, hb1, acc[0][1], 0, 0, 0);
            acc[1][0] = __builtin_amdgcn_mfma_f32_16x16x32_bf16(wa1, hb0, acc[1][0], 0, 0, 0);
            acc[1][1] = __builtin_amdgcn_mfma_f32_16x16x32_bf16(wa1, hb1, acc[1][1], 0, 0, 0);
        }
        #pragma unroll
        for (int mi = 0; mi < 2; ++mi) {
            #pragma unroll
            for (int n = 0; n < 2; ++n) {
                int row = n * 16 + lr;
                int col = (2 * w + mi) * 16 + lq * 4;
                uint2 s;
                s.x = pk2(softplus_fast(acc[mi][n][0]), softplus_fast(acc[mi][n][1]));
                s.y = pk2(softplus_fast(acc[mi][n][2]), softplus_fast(acc[mi][n][3]));
                *(uint2*)&Ha[row * LDA + col] = s;
            }
        }
    }
    __syncthreads();

    // ---- stage e -> Az (z dead; e consumed from G3 on; G1/G2 barriers cover) ----
    {
        int r = tid >> 4, c4 = (tid & 15) * 4;
        float4 ev = *(const float4*)(e + (rowbase + r) * 64 + c4);
        uint2 s; s.x = pk2(ev.x, ev.y); s.y = pk2(ev.z, ev.w);
        *(uint2*)&Az[r * LDZ + c4] = s;
    }

    // ============ G1: h1^T = W1frag @ h0^T + cst1 -> Hb ============
    {
        floatx4 acc[2][2];
        #pragma unroll
        for (int mi = 0; mi < 2; ++mi) {
            floatx4 c = *(const floatx4*)&cst[256 + (2 * w + mi) * 16 + lq * 4];
            acc[mi][0] = c; acc[mi][1] = c;
        }
        #pragma unroll
        for (int kt = 0; kt < 8; ++kt) {
            short8 wa0 = *(const short8*)(pw1 + (kt)     * 512);
            short8 wa1 = *(const short8*)(pw1 + (8 + kt) * 512);
            short8 hb0 = *(const short8*)&Ha[lr * LDA + kt * 32 + lq * 8];
            short8 hb1 = *(const short8*)&Ha[(16 + lr) * LDA + kt * 32 + lq * 8];
            acc[0][0] = __builtin_amdgcn_mfma_f32_16x16x32_bf16(wa0, hb0, acc[0][0], 0, 0, 0);
            acc[0][1] = __builtin_amdgcn_mfma_f32_16x16x32_bf16(wa0, hb1, acc[0][1], 0, 0, 0);
            acc[1][0] = __builtin_amdgcn_mfma_f32_16x16x32_bf16(wa1, hb0, acc[1][0], 0, 0, 0);
            acc[1][1] = __builtin_amdgcn_mfma_f32_16x16x32_bf16(wa1, hb1, acc[1][1], 0, 0, 0);
        }
        #pragma unroll
        for (int mi = 0; mi < 2; ++mi) {
            #pragma unroll
            for (int n = 0; n < 2; ++n) {
                int row = n * 16 + lr;
                int col = (2 * w + mi) * 16 + lq * 4;
                uint2 s;
                s.x = pk2(softplus_fast(acc[mi][n][0]), softplus_fast(acc[mi][n][1]));
                s.y = pk2(softplus_fast(acc[mi][n][2]), softplus_fast(acc[mi][n][3]));
                *(uint2*)&Hb[row * LDA + col] = s;
            }
        }
    }
    __syncthreads();

    // ============ G2: dx^T = W2frag @ h1^T + cst2 -> out[:, :64] ============
    {
        floatx4 a0 = *(const floatx4*)&cst[512 + mt2 * 16 + lq * 4];
        #pragma unroll
        for (int kt = 0; kt < 8; ++kt) {
            short8 wa = *(const short8*)(pw2 + kt * 512);
            short8 hb = *(const short8*)&Hb[(n2 * 16 + lr) * LDA + kt * 32 + lq * 8];
            a0 = __builtin_amdgcn_mfma_f32_16x16x32_bf16(wa, hb, a0, 0, 0, 0);
        }
        int batch = n2 * 16 + lr;
        int col = mt2 * 16 + lq * 4;
        float* op = out + (rowbase + batch) * 65 + col;
        op[0] = a0[0]; op[1] = a0[1]; op[2] = a0[2]; op[3] = a0[3];
    }
    __syncthreads();   // all Hb (h1) reads done before G3 overwrites Hb

    // ==== G3: g2^T = W2Tfrag @ e^T;  p1 = g2*(1-exp(-h1)) -> Hb IN PLACE ====
    {
        floatx4 acc[2][2];
        acc[0][0] = zero; acc[0][1] = zero; acc[1][0] = zero; acc[1][1] = zero;
        #pragma unroll
        for (int kt = 0; kt < 2; ++kt) {
            short8 wa0 = *(const short8*)(pw3 + (kt)     * 512);
            short8 wa1 = *(const short8*)(pw3 + (2 + kt) * 512);
            short8 eb0 = *(const short8*)&Az[lr * LDZ + kt * 32 + lq * 8];
            short8 eb1 = *(const short8*)&Az[(16 + lr) * LDZ + kt * 32 + lq * 8];
            acc[0][0] = __builtin_amdgcn_mfma_f32_16x16x32_bf16(wa0, eb0, acc[0][0], 0, 0, 0);
            acc[0][1] = __builtin_amdgcn_mfma_f32_16x16x32_bf16(wa0, eb1, acc[0][1], 0, 0, 0);
            acc[1][0] = __builtin_amdgcn_mfma_f32_16x16x32_bf16(wa1, eb0, acc[1][0], 0, 0, 0);
            acc[1][1] = __builtin_amdgcn_mfma_f32_16x16x32_bf16(wa1, eb1, acc[1][1], 0, 0, 0);
        }
        #pragma unroll
        for (int mi = 0; mi < 2; ++mi) {
            #pragma unroll
            for (int n = 0; n < 2; ++n) {
                int row = n * 16 + lr;
                int col = (2 * w + mi) * 16 + lq * 4;
                uint2 old = *(const uint2*)&Hb[row * LDA + col];
                float g0v = acc[mi][n][0], g1v = acc[mi][n][1];
                float g2v = acc[mi][n][2], g3v = acc[mi][n][3];
                float s0 = fmaf(-g0v, __expf(-lo2f(old.x)), g0v);
                float s1 = fmaf(-g1v, __expf(-hi2f(old.x)), g1v);
                float s2 = fmaf(-g2v, __expf(-lo2f(old.y)), g2v);
                float s3 = fmaf(-g3v, __expf(-hi2f(old.y)), g3v);
                uint2 s; s.x = pk2(s0, s1); s.y = pk2(s2, s3);
                *(uint2*)&Hb[row * LDA + col] = s;
            }
        }
    }
    __syncthreads();

    // ==== G4: g1^T = W1Tfrag @ p1^T;  p0 = g1*(1-exp(-h0)) -> Ha IN PLACE ====
    {
        floatx4 acc[2][2];
        acc[0][0] = zero; acc[0][1] = zero; acc[1][0] = zero; acc[1][1] = zero;
        #pragma unroll
        for (int kt = 0; kt < 8; ++kt) {
            short8 wa0 = *(const short8*)(pw4 + (kt)     * 512);
            short8 wa1 = *(const short8*)(pw4 + (8 + kt) * 512);
            short8 pb0 = *(const short8*)&Hb[lr * LDA + kt * 32 + lq * 8];
            short8 pb1 = *(const short8*)&Hb[(16 + lr) * LDA + kt * 32 + lq * 8];
            acc[0][0] = __builtin_amdgcn_mfma_f32_16x16x32_bf16(wa0, pb0, acc[0][0], 0, 0, 0);
            acc[0][1] = __builtin_amdgcn_mfma_f32_16x16x32_bf16(wa0, pb1, acc[0][1], 0, 0, 0);
            acc[1][0] = __builtin_amdgcn_mfma_f32_16x16x32_bf16(wa1, pb0, acc[1][0], 0, 0, 0);
            acc[1][1] = __builtin_amdgcn_mfma_f32_16x16x32_bf16(wa1, pb1, acc[1][1], 0, 0, 0);
        }
        #pragma unroll
        for (int mi = 0; mi < 2; ++mi) {
            #pragma unroll
            for (int n = 0; n < 2; ++n) {
                int row = n * 16 + lr;
                int col = (2 * w + mi) * 16 + lq * 4;
                uint2 old = *(const uint2*)&Ha[row * LDA + col];
                float g0v = acc[mi][n][0], g1v = acc[mi][n][1];
                float g2v = acc[mi][n][2], g3v = acc[mi][n][3];
                float s0 = fmaf(-g0v, __expf(-lo2f(old.x)), g0v);
                float s1 = fmaf(-g1v, __expf(-hi2f(old.x)), g1v);
                float s2 = fmaf(-g2v, __expf(-lo2f(old.y)), g2v);
                float s3 = fmaf(-g3v, __expf(-hi2f(old.y)), g3v);
                uint2 s; s.x = pk2(s0, s1); s.y = pk2(s2, s3);
                *(uint2*)&Ha[row * LDA + col] = s;
            }
        }
    }
    __syncthreads();

    // ==== G5: g0^T = W0Tfrag @ p0^T;  div = sum(g0*e);  out[:,64] = -div ====
    {
        floatx4 a0 = zero;
        #pragma unroll
        for (int kt = 0; kt < 8; ++kt) {
            short8 wa = *(const short8*)(pw5 + kt * 512);
            short8 pb = *(const short8*)&Ha[(n2 * 16 + lr) * LDA + kt * 32 + lq * 8];
            a0 = __builtin_amdgcn_mfma_f32_16x16x32_bf16(wa, pb, a0, 0, 0, 0);
        }
        int batch = n2 * 16 + lr;
        float4 ev = *(const float4*)(e + (rowbase + batch) * 64 + mt2 * 16 + lq * 4);
        float v = a0[0] * ev.x + a0[1] * ev.y + a0[2] * ev.z + a0[3] * ev.w;
        v += __shfl_xor(v, 16, 64);
        v += __shfl_xor(v, 32, 64);
        if (lq == 0) divp[mt2][batch] = v;
    }
    __syncthreads();
    if (tid < RB)
        out[(rowbase + tid) * 65 + 64] =
            -(divp[0][tid] + divp[1][tid] + divp[2][tid] + divp[3][tid]);
}

// ---------------- fp32 vector fallback (used only if ws_size too small) ----------------
#define FNT 256
__global__ __launch_bounds__(FNT, 2)
void ode_fallback(const float* __restrict__ tptr,
                  const float* __restrict__ y, const float* __restrict__ e,
                  const float* __restrict__ W0, const float* __restrict__ b0,
                  const float* __restrict__ W1, const float* __restrict__ b1,
                  const float* __restrict__ W2, const float* __restrict__ b2,
                  float* __restrict__ out)
{
    __shared__ float H0[RB * 257];
    __shared__ float H1[RB * 257];
    __shared__ float ZE[RB * 68];

    const int tid = threadIdx.x;
    const int rowbase = blockIdx.x * RB;
    const float tval = tptr[0];
    const int cg = tid & 31, rg = tid >> 5;
    const int cg2 = tid & 15, rg2 = tid >> 4;

    {
        const int d = tid & 63, r0 = tid >> 6;
        for (int r = r0; r < RB; r += FNT / 64)
            ZE[r * 68 + d] = y[(rowbase + r) * 65 + d];
    }
    __syncthreads();

    float acc[4][8];
    float acc2[2][4];

    for (int i = 0; i < 4; ++i) for (int j = 0; j < 8; ++j) acc[i][j] = 0.0f;
    for (int s = 0; s < 64; ++s) {
        float b[8];
        for (int j = 0; j < 8; ++j) b[j] = W0[(cg * 8 + j) * 65 + 1 + s];
        float a[4];
        for (int i = 0; i < 4; ++i) a[i] = ZE[(rg * 4 + i) * 68 + s];
        for (int i = 0; i < 4; ++i) for (int j = 0; j < 8; ++j)
            acc[i][j] = fmaf(a[i], b[j], acc[i][j]);
    }
    for (int i = 0; i < 4; ++i) for (int j = 0; j < 8; ++j) {
        int n = cg * 8 + j;
        H0[(rg * 4 + i) * 257 + n] = softplus_fast(acc[i][j] + tval * W0[n * 65] + b0[n]);
    }
    __syncthreads();

    for (int idx = tid; idx < RB * 16; idx += FNT) {
        int r = idx >> 4, c = idx & 15;
        *(float4*)(&ZE[r * 68 + c * 4]) = *(const float4*)(e + (rowbase + r) * 64 + c * 4);
    }

    for (int i = 0; i < 4; ++i) for (int j = 0; j < 8; ++j) acc[i][j] = 0.0f;
    for (int s = 0; s < 256; ++s) {
        float b[8];
        for (int j = 0; j < 8; ++j) b[j] = W1[(cg * 8 + j) * 257 + 1 + s];
        float a[4];
        for (int i = 0; i < 4; ++i) a[i] = H0[(rg * 4 + i) * 257 + s];
        for (int i = 0; i < 4; ++i) for (int j = 0; j < 8; ++j)
            acc[i][j] = fmaf(a[i], b[j], acc[i][j]);
    }
    for (int i = 0; i < 4; ++i) for (int j = 0; j < 8; ++j) {
        int n = cg * 8 + j;
        H1[(rg * 4 + i) * 257 + n] = softplus_fast(acc[i][j] + tval * W1[n * 257] + b1[n]);
    }
    __syncthreads();

    for (int i = 0; i < 2; ++i) for (int j = 0; j < 4; ++j) acc2[i][j] = 0.0f;
    for (int s = 0; s < 256; ++s) {
        float b[4];
        for (int j = 0; j < 4; ++j) b[j] = W2[(cg2 * 4 + j) * 257 + 1 + s];
        float a[2];
        for (int i = 0; i < 2; ++i) a[i] = H1[(rg2 * 2 + i) * 257 + s];
        for (int i = 0; i < 2; ++i) for (int j = 0; j < 4; ++j)
            acc2[i][j] = fmaf(a[i], b[j], acc2[i][j]);
    }
    for (int i = 0; i < 2; ++i) for (int j = 0; j < 4; ++j) {
        int n = cg2 * 4 + j;
        out[(rowbase + rg2 * 2 + i) * 65 + n] = acc2[i][j] + tval * W2[n * 257] + b2[n];
    }
    __syncthreads();

    for (int i = 0; i < 4; ++i) for (int j = 0; j < 8; ++j) acc[i][j] = 0.0f;
    for (int s = 0; s < 64; ++s) {
        float b[8];
        for (int j = 0; j < 8; ++j) b[j] = W2[s * 257 + 1 + cg * 8 + j];
        float a[4];
        for (int i = 0; i < 4; ++i) a[i] = ZE[(rg * 4 + i) * 68 + s];
        for (int i = 0; i < 4; ++i) for (int j = 0; j < 8; ++j)
            acc[i][j] = fmaf(a[i], b[j], acc[i][j]);
    }
    for (int i = 0; i < 4; ++i) for (int j = 0; j < 8; ++j) {
        int r = rg * 4 + i, n = cg * 8 + j;
        float h = H1[r * 257 + n];
        H1[r * 257 + n] = acc[i][j] * (1.0f - __expf(-h));
    }
    __syncthreads();

    for (int i = 0; i < 4; ++i) for (int j = 0; j < 8; ++j) acc[i][j] = 0.0f;
    for (int s = 0; s < 256; ++s) {
        float b[8];
        for (int j = 0; j < 8; ++j) b[j] = W1[s * 257 + 1 + cg * 8 + j];
        float a[4];
        for (int i = 0; i < 4; ++i) a[i] = H1[(rg * 4 + i) * 257 + s];
        for (int i = 0; i < 4; ++i) for (int j = 0; j < 8; ++j)
            acc[i][j] = fmaf(a[i], b[j], acc[i][j]);
    }
    for (int i = 0; i < 4; ++i) for (int j = 0; j < 8; ++j) {
        int r = rg * 4 + i, n = cg * 8 + j;
        float h = H0[r * 257 + n];
        H0[r * 257 + n] = acc[i][j] * (1.0f - __expf(-h));
    }
    __syncthreads();

    for (int i = 0; i < 2; ++i) for (int j = 0; j < 4; ++j) acc2[i][j] = 0.0f;
    for (int s = 0; s < 256; ++s) {
        float b[4];
        for (int j = 0; j < 4; ++j) b[j] = W0[s * 65 + 1 + cg2 * 4 + j];
        float a[2];
        for (int i = 0; i < 2; ++i) a[i] = H0[(rg2 * 2 + i) * 257 + s];
        for (int i = 0; i < 2; ++i) for (int j = 0; j < 4; ++j)
            acc2[i][j] = fmaf(a[i], b[j], acc2[i][j]);
    }
    float pA = 0.0f, pB = 0.0f;
    for (int j = 0; j < 4; ++j) {
        int n = cg2 * 4 + j;
        pA = fmaf(acc2[0][j], ZE[(rg2 * 2 + 0) * 68 + n], pA);
        pB = fmaf(acc2[1][j], ZE[(rg2 * 2 + 1) * 68 + n], pB);
    }
    for (int off = 8; off > 0; off >>= 1) {
        pA += __shfl_down(pA, off, 16);
        pB += __shfl_down(pB, off, 16);
    }
    if (cg2 == 0) {
        out[(rowbase + rg2 * 2 + 0) * 65 + 64] = -pA;
        out[(rowbase + rg2 * 2 + 1) * 65 + 64] = -pB;
    }
}

extern "C" void kernel_launch(void* const* d_in, const int* in_sizes, int n_in,
                              void* d_out, int out_size, void* d_ws, size_t ws_size,
                              hipStream_t stream)
{
    const float* t  = (const float*)d_in[0];
    const float* y  = (const float*)d_in[1];
    const float* e  = (const float*)d_in[2];
    const float* W0 = (const float*)d_in[3];
    const float* b0 = (const float*)d_in[4];
    const float* W1 = (const float*)d_in[5];
    const float* b1 = (const float*)d_in[6];
    const float* W2 = (const float*)d_in[7];
    const float* b2 = (const float*)d_in[8];
    float* out = (float*)d_out;

    const int B = in_sizes[1] / 65;

    if (ws_size >= (size_t)WS_BYTES) {
        prep_pack<<<(PACK_ELEMS + 576 + 255) / 256, 256, 0, stream>>>(
            t, W0, b0, W1, b1, W2, b2, (short*)d_ws);
        ode_mfma<<<B / RB, NT, 0, stream>>>(y, e, (const short*)d_ws, out);
    } else {
        ode_fallback<<<B / RB, FNT, 0, stream>>>(t, y, e, W0, b0, W1, b1, W2, b2, out);
    }
}

// Round 8
// 305.349 us; speedup vs baseline: 1.1184x; 1.0740x over previous
//
#include <hip/hip_runtime.h>
#include <math.h>

// FFJORD ODE func: 3-layer MLP fwd + VJP + Hutchinson divergence.
// B=262144 rows, D=64, H=256. bf16 MFMA (16x16x32), fp32 accumulate.
// R8: RB=64 rows/block (NT=512, 8 waves, 2 blocks/CU): halves per-row weight
//     L2 traffic and barrier count; wave tile = 2 nout-tiles x 4 batch-tiles
//     (8 independent MFMA chains -> deeper ILP window per phase).
//
// ws layout (UNCHANGED):
//   bf16 packed W-fragments (frag = 512 bf16, frag_id = t*KT+kt):
//     P0 @ elem 0      : fwd L0  W0[n][1+s]  (KT=2,  32 frags)
//     P1 @ elem 16384  : fwd L1  W1[n][1+s]  (KT=8, 128 frags)
//     P2 @ elem 81920  : fwd L2  W2[n][1+s]  (KT=8,  32 frags)
//     P3 @ elem 98304  : bwd g2  W2[s][1+n]  (KT=2,  32 frags)
//     P4 @ elem 114688 : bwd g1  W1[s][1+n]  (KT=8, 128 frags)
//     P5 @ elem 180224 : bwd g0  W0[s][1+n]  (KT=8,  32 frags)
//   fp32 cst @ byte 393216: cst0[256], cst1[256], cst2[64] = t*W[:,0]+b

typedef __attribute__((ext_vector_type(8))) short short8;
typedef __attribute__((ext_vector_type(4))) float floatx4;

#define NT 512    // 8 waves
#define RB 64
#define LDA 264   // bf16 row stride (528 B)
#define LDZ 72

#define P0_OFF 0
#define P1_OFF 16384
#define P2_OFF 81920
#define P3_OFF 98304
#define P4_OFF 114688
#define P5_OFF 180224
#define PACK_ELEMS 196608
#define CST_BYTE_OFF (PACK_ELEMS * 2)
#define WS_BYTES (CST_BYTE_OFF + 576 * 4)

static __device__ __forceinline__ short f2bf(float f) {
    union { float f; unsigned u; } v; v.f = f;
    unsigned r = v.u + 0x7FFFu + ((v.u >> 16) & 1u);   // RNE (prep only)
    return (short)(r >> 16);
}
// pack two floats -> one dword of 2 bf16 (lo, hi), round-half-up (<=1/2 ulp).
static __device__ __forceinline__ unsigned pk2(float lo, float hi) {
    union { float f; unsigned u; } a, b; a.f = lo; b.f = hi;
    return ((b.u + 0x8000u) & 0xFFFF0000u) | ((a.u + 0x8000u) >> 16);
}
static __device__ __forceinline__ float lo2f(unsigned u) {
    union { unsigned u; float f; } v; v.u = u << 16; return v.f;
}
static __device__ __forceinline__ float hi2f(unsigned u) {
    union { unsigned u; float f; } v; v.u = u & 0xFFFF0000u; return v.f;
}
// Fast softplus: native v_exp_f32/v_log_f32; error ~2^-24 abs, invisible at bf16.
static __device__ __forceinline__ float softplus_fast(float x) {
    float u = __expf(-fabsf(x));
    return fmaxf(x, 0.0f) + __logf(1.0f + u);
}

__global__ void prep_pack(const float* __restrict__ t,
                          const float* __restrict__ W0, const float* __restrict__ b0,
                          const float* __restrict__ W1, const float* __restrict__ b1,
                          const float* __restrict__ W2, const float* __restrict__ b2,
                          short* __restrict__ wsp)
{
    int i = blockIdx.x * blockDim.x + threadIdx.x;
    if (i < PACK_ELEMS) {
        int jin, ld, mode, kt, nt; const float* src;
        if      (i < P1_OFF) { jin = i - P0_OFF; src = W0; ld = 65;  mode = 0;
                               int f = jin >> 9; kt = f & 1; nt = f >> 1; }
        else if (i < P2_OFF) { jin = i - P1_OFF; src = W1; ld = 257; mode = 0;
                               int f = jin >> 9; kt = f & 7; nt = f >> 3; }
        else if (i < P3_OFF) { jin = i - P2_OFF; src = W2; ld = 257; mode = 0;
                               int f = jin >> 9; kt = f & 7; nt = f >> 3; }
        else if (i < P4_OFF) { jin = i - P3_OFF; src = W2; ld = 257; mode = 1;
                               int f = jin >> 9; kt = f & 1; nt = f >> 1; }
        else if (i < P5_OFF) { jin = i - P4_OFF; src = W1; ld = 257; mode = 1;
                               int f = jin >> 9; kt = f & 7; nt = f >> 3; }
        else                 { jin = i - P5_OFF; src = W0; ld = 65;  mode = 1;
                               int f = jin >> 9; kt = f & 7; nt = f >> 3; }
        int r = jin & 511;
        int lane = r >> 3, jj = r & 7;
        int k = kt * 32 + (lane >> 4) * 8 + jj;
        int n = nt * 16 + (lane & 15);
        float v = (mode == 0) ? src[n * ld + 1 + k] : src[k * ld + 1 + n];
        wsp[i] = f2bf(v);
    } else if (i < PACK_ELEMS + 576) {
        int ci = i - PACK_ELEMS;
        float tv = t[0];
        float* cst = (float*)((char*)wsp + CST_BYTE_OFF);
        float v;
        if (ci < 256)      v = tv * W0[ci * 65] + b0[ci];
        else if (ci < 512) { int n = ci - 256; v = tv * W1[n * 257] + b1[n]; }
        else               { int n = ci - 512; v = tv * W2[n * 257] + b2[n]; }
        cst[ci] = v;
    }
}

__global__ __launch_bounds__(NT, 4)   // 4 waves/EU -> 2 blocks/CU (8-wave blocks)
void ode_mfma(const float* __restrict__ y, const float* __restrict__ e,
              const short* __restrict__ wsp, float* __restrict__ out)
{
    __shared__ __align__(16) short Az[RB * LDZ];   // z bf16, then e bf16 (after G0)
    __shared__ __align__(16) short Ha[RB * LDA];   // h0, then p0 (in place)
    __shared__ __align__(16) short Hb[RB * LDA];   // h1, then p1 (in place)
    __shared__ float divp[4][RB];
    // LDS total: 9216 + 2*33792 + 1024 = 77824 B -> 2 blocks/CU

    const int tid = threadIdx.x;
    const int rowbase = blockIdx.x * RB;
    const int w = tid >> 6, l = tid & 63;
    const int lr = l & 15, lq = l >> 4;
    // Big GEMMs (256 nout): wave w owns nout-tiles {2w,2w+1}, batch-tiles 0..3.
    // Small GEMMs (64 nout): wave = (mt2 = w&3 nout-tile, batch-tiles {2n2,2n2+1}).
    const int mt2 = w & 3, n2 = w >> 2;
    const float* cst = (const float*)((const char*)wsp + CST_BYTE_OFF);

    // hoisted per-wave fragment base pointers
    const short* pw0 = wsp + P0_OFF + (4 * w) * 512 + l * 8;      // frag (2w+mi)*2+kt
    const short* pw1 = wsp + P1_OFF + (16 * w) * 512 + l * 8;     // frag (2w+mi)*8+kt
    const short* pw2 = wsp + P2_OFF + (mt2 * 8) * 512 + l * 8;
    const short* pw3 = wsp + P3_OFF + (4 * w) * 512 + l * 8;
    const short* pw4 = wsp + P4_OFF + (16 * w) * 512 + l * 8;
    const short* pw5 = wsp + P5_OFF + (mt2 * 8) * 512 + l * 8;

    // ---- stage z = y[:, :64] (8 elems/thread -> 1 b128 write) ----
    {
        int r = tid >> 3, c8 = (tid & 7) * 8;
        const float* yp = y + (rowbase + r) * 65 + c8;
        uint4 s;
        s.x = pk2(yp[0], yp[1]); s.y = pk2(yp[2], yp[3]);
        s.z = pk2(yp[4], yp[5]); s.w = pk2(yp[6], yp[7]);
        *(uint4*)&Az[r * LDZ + c8] = s;
    }
    __syncthreads();

    const floatx4 zero = {0.f, 0.f, 0.f, 0.f};

    // ============ G0: h0^T = W0frag @ z^T + cst0;  softplus -> Ha ============
    {
        floatx4 acc[2][4];   // [mi][bt]
        #pragma unroll
        for (int mi = 0; mi < 2; ++mi) {
            floatx4 c = *(const floatx4*)&cst[(2 * w + mi) * 16 + lq * 4];
            #pragma unroll
            for (int bt = 0; bt < 4; ++bt) acc[mi][bt] = c;
        }
        #pragma unroll
        for (int kt = 0; kt < 2; ++kt) {
            short8 wa0 = *(const short8*)(pw0 + (kt)     * 512);
            short8 wa1 = *(const short8*)(pw0 + (2 + kt) * 512);
            #pragma unroll
            for (int bt = 0; bt < 4; ++bt) {
                short8 hb = *(const short8*)&Az[(bt * 16 + lr) * LDZ + kt * 32 + lq * 8];
                acc[0][bt] = __builtin_amdgcn_mfma_f32_16x16x32_bf16(wa0, hb, acc[0][bt], 0, 0, 0);
                acc[1][bt] = __builtin_amdgcn_mfma_f32_16x16x32_bf16(wa1, hb, acc[1][bt], 0, 0, 0);
            }
        }
        #pragma unroll
        for (int mi = 0; mi < 2; ++mi) {
            #pragma unroll
            for (int bt = 0; bt < 4; ++bt) {
                int row = bt * 16 + lr;
                int col = (2 * w + mi) * 16 + lq * 4;
                uint2 s;
                s.x = pk2(softplus_fast(acc[mi][bt][0]), softplus_fast(acc[mi][bt][1]));
                s.y = pk2(softplus_fast(acc[mi][bt][2]), softplus_fast(acc[mi][bt][3]));
                *(uint2*)&Ha[row * LDA + col] = s;
            }
        }
    }
    __syncthreads();

    // ---- stage e -> Az (z dead; e consumed from G3 on; G1/G2 barriers cover) ----
    {
        int r = tid >> 3, c8 = (tid & 7) * 8;
        const float* ep = e + (rowbase + r) * 64 + c8;
        float4 e0 = *(const float4*)(ep);
        float4 e1 = *(const float4*)(ep + 4);
        uint4 s;
        s.x = pk2(e0.x, e0.y); s.y = pk2(e0.z, e0.w);
        s.z = pk2(e1.x, e1.y); s.w = pk2(e1.z, e1.w);
        *(uint4*)&Az[r * LDZ + c8] = s;
    }

    // ============ G1: h1^T = W1frag @ h0^T + cst1 -> Hb ============
    {
        floatx4 acc[2][4];
        #pragma unroll
        for (int mi = 0; mi < 2; ++mi) {
            floatx4 c = *(const floatx4*)&cst[256 + (2 * w + mi) * 16 + lq * 4];
            #pragma unroll
            for (int bt = 0; bt < 4; ++bt) acc[mi][bt] = c;
        }
        #pragma unroll
        for (int kt = 0; kt < 8; ++kt) {
            short8 wa0 = *(const short8*)(pw1 + (kt)     * 512);
            short8 wa1 = *(const short8*)(pw1 + (8 + kt) * 512);
            #pragma unroll
            for (int bt = 0; bt < 4; ++bt) {
                short8 hb = *(const short8*)&Ha[(bt * 16 + lr) * LDA + kt * 32 + lq * 8];
                acc[0][bt] = __builtin_amdgcn_mfma_f32_16x16x32_bf16(wa0, hb, acc[0][bt], 0, 0, 0);
                acc[1][bt] = __builtin_amdgcn_mfma_f32_16x16x32_bf16(wa1, hb, acc[1][bt], 0, 0, 0);
            }
        }
        #pragma unroll
        for (int mi = 0; mi < 2; ++mi) {
            #pragma unroll
            for (int bt = 0; bt < 4; ++bt) {
                int row = bt * 16 + lr;
                int col = (2 * w + mi) * 16 + lq * 4;
                uint2 s;
                s.x = pk2(softplus_fast(acc[mi][bt][0]), softplus_fast(acc[mi][bt][1]));
                s.y = pk2(softplus_fast(acc[mi][bt][2]), softplus_fast(acc[mi][bt][3]));
                *(uint2*)&Hb[row * LDA + col] = s;
            }
        }
    }
    __syncthreads();

    // ============ G2: dx^T = W2frag @ h1^T + cst2 -> out[:, :64] ============
    {
        floatx4 a[2];
        {
            floatx4 c = *(const floatx4*)&cst[512 + mt2 * 16 + lq * 4];
            a[0] = c; a[1] = c;
        }
        #pragma unroll
        for (int kt = 0; kt < 8; ++kt) {
            short8 wa = *(const short8*)(pw2 + kt * 512);
            #pragma unroll
            for (int b2i = 0; b2i < 2; ++b2i) {
                short8 hb = *(const short8*)&Hb[((2 * n2 + b2i) * 16 + lr) * LDA + kt * 32 + lq * 8];
                a[b2i] = __builtin_amdgcn_mfma_f32_16x16x32_bf16(wa, hb, a[b2i], 0, 0, 0);
            }
        }
        #pragma unroll
        for (int b2i = 0; b2i < 2; ++b2i) {
            int batch = (2 * n2 + b2i) * 16 + lr;
            int col = mt2 * 16 + lq * 4;
            float* op = out + (rowbase + batch) * 65 + col;
            op[0] = a[b2i][0]; op[1] = a[b2i][1]; op[2] = a[b2i][2]; op[3] = a[b2i][3];
        }
    }
    __syncthreads();   // all Hb (h1) reads done before G3 overwrites Hb

    // ==== G3: g2^T = W2Tfrag @ e^T;  p1 = g2*(1-exp(-h1)) -> Hb IN PLACE ====
    {
        floatx4 acc[2][4];
        #pragma unroll
        for (int mi = 0; mi < 2; ++mi)
            #pragma unroll
            for (int bt = 0; bt < 4; ++bt) acc[mi][bt] = zero;
        #pragma unroll
        for (int kt = 0; kt < 2; ++kt) {
            short8 wa0 = *(const short8*)(pw3 + (kt)     * 512);
            short8 wa1 = *(const short8*)(pw3 + (2 + kt) * 512);
            #pragma unroll
            for (int bt = 0; bt < 4; ++bt) {
                short8 eb = *(const short8*)&Az[(bt * 16 + lr) * LDZ + kt * 32 + lq * 8];
                acc[0][bt] = __builtin_amdgcn_mfma_f32_16x16x32_bf16(wa0, eb, acc[0][bt], 0, 0, 0);
                acc[1][bt] = __builtin_amdgcn_mfma_f32_16x16x32_bf16(wa1, eb, acc[1][bt], 0, 0, 0);
            }
        }
        #pragma unroll
        for (int mi = 0; mi < 2; ++mi) {
            #pragma unroll
            for (int bt = 0; bt < 4; ++bt) {
                int row = bt * 16 + lr;
                int col = (2 * w + mi) * 16 + lq * 4;
                uint2 old = *(const uint2*)&Hb[row * LDA + col];
                float g0v = acc[mi][bt][0], g1v = acc[mi][bt][1];
                float g2v = acc[mi][bt][2], g3v = acc[mi][bt][3];
                float s0 = fmaf(-g0v, __expf(-lo2f(old.x)), g0v);
                float s1 = fmaf(-g1v, __expf(-hi2f(old.x)), g1v);
                float s2 = fmaf(-g2v, __expf(-lo2f(old.y)), g2v);
                float s3 = fmaf(-g3v, __expf(-hi2f(old.y)), g3v);
                uint2 s; s.x = pk2(s0, s1); s.y = pk2(s2, s3);
                *(uint2*)&Hb[row * LDA + col] = s;
            }
        }
    }
    __syncthreads();

    // ==== G4: g1^T = W1Tfrag @ p1^T;  p0 = g1*(1-exp(-h0)) -> Ha IN PLACE ====
    {
        floatx4 acc[2][4];
        #pragma unroll
        for (int mi = 0; mi < 2; ++mi)
            #pragma unroll
            for (int bt = 0; bt < 4; ++bt) acc[mi][bt] = zero;
        #pragma unroll
        for (int kt = 0; kt < 8; ++kt) {
            short8 wa0 = *(const short8*)(pw4 + (kt)     * 512);
            short8 wa1 = *(const short8*)(pw4 + (8 + kt) * 512);
            #pragma unroll
            for (int bt = 0; bt < 4; ++bt) {
                short8 pb = *(const short8*)&Hb[(bt * 16 + lr) * LDA + kt * 32 + lq * 8];
                acc[0][bt] = __builtin_amdgcn_mfma_f32_16x16x32_bf16(wa0, pb, acc[0][bt], 0, 0, 0);
                acc[1][bt] = __builtin_amdgcn_mfma_f32_16x16x32_bf16(wa1, pb, acc[1][bt], 0, 0, 0);
            }
        }
        #pragma unroll
        for (int mi = 0; mi < 2; ++mi) {
            #pragma unroll
            for (int bt = 0; bt < 4; ++bt) {
                int row = bt * 16 + lr;
                int col = (2 * w + mi) * 16 + lq * 4;
                uint2 old = *(const uint2*)&Ha[row * LDA + col];
                float g0v = acc[mi][bt][0], g1v = acc[mi][bt][1];
                float g2v = acc[mi][bt][2], g3v = acc[mi][bt][3];
                float s0 = fmaf(-g0v, __expf(-lo2f(old.x)), g0v);
                float s1 = fmaf(-g1v, __expf(-hi2f(old.x)), g1v);
                float s2 = fmaf(-g2v, __expf(-lo2f(old.y)), g2v);
                float s3 = fmaf(-g3v, __expf(-hi2f(old.y)), g3v);
                uint2 s; s.x = pk2(s0, s1); s.y = pk2(s2, s3);
                *(uint2*)&Ha[row * LDA + col] = s;
            }
        }
    }
    __syncthreads();

    // ==== G5: g0^T = W0Tfrag @ p0^T;  div = sum(g0*e);  out[:,64] = -div ====
    {
        floatx4 a[2];
        a[0] = zero; a[1] = zero;
        #pragma unroll
        for (int kt = 0; kt < 8; ++kt) {
            short8 wa = *(const short8*)(pw5 + kt * 512);
            #pragma unroll
            for (int b2i = 0; b2i < 2; ++b2i) {
                short8 pb = *(const short8*)&Ha[((2 * n2 + b2i) * 16 + lr) * LDA + kt * 32 + lq * 8];
                a[b2i] = __builtin_amdgcn_mfma_f32_16x16x32_bf16(wa, pb, a[b2i], 0, 0, 0);
            }
        }
        #pragma unroll
        for (int b2i = 0; b2i < 2; ++b2i) {
            int batch = (2 * n2 + b2i) * 16 + lr;
            float4 ev = *(const float4*)(e + (rowbase + batch) * 64 + mt2 * 16 + lq * 4);
            float v = a[b2i][0] * ev.x + a[b2i][1] * ev.y + a[b2i][2] * ev.z + a[b2i][3] * ev.w;
            v += __shfl_xor(v, 16, 64);
            v += __shfl_xor(v, 32, 64);
            if (lq == 0) divp[mt2][batch] = v;
        }
    }
    __syncthreads();
    if (tid < RB)
        out[(rowbase + tid) * 65 + 64] =
            -(divp[0][tid] + divp[1][tid] + divp[2][tid] + divp[3][tid]);
}

// ---------------- fp32 vector fallback (used only if ws_size too small) ----------------
#define FNT 256
#define FRB 32
__global__ __launch_bounds__(FNT, 2)
void ode_fallback(const float* __restrict__ tptr,
                  const float* __restrict__ y, const float* __restrict__ e,
                  const float* __restrict__ W0, const float* __restrict__ b0,
                  const float* __restrict__ W1, const float* __restrict__ b1,
                  const float* __restrict__ W2, const float* __restrict__ b2,
                  float* __restrict__ out)
{
    __shared__ float H0[FRB * 257];
    __shared__ float H1[FRB * 257];
    __shared__ float ZE[FRB * 68];

    const int tid = threadIdx.x;
    const int rowbase = blockIdx.x * FRB;
    const float tval = tptr[0];
    const int cg = tid & 31, rg = tid >> 5;
    const int cg2 = tid & 15, rg2 = tid >> 4;

    {
        const int d = tid & 63, r0 = tid >> 6;
        for (int r = r0; r < FRB; r += FNT / 64)
            ZE[r * 68 + d] = y[(rowbase + r) * 65 + d];
    }
    __syncthreads();

    float acc[4][8];
    float acc2[2][4];

    for (int i = 0; i < 4; ++i) for (int j = 0; j < 8; ++j) acc[i][j] = 0.0f;
    for (int s = 0; s < 64; ++s) {
        float b[8];
        for (int j = 0; j < 8; ++j) b[j] = W0[(cg * 8 + j) * 65 + 1 + s];
        float a[4];
        for (int i = 0; i < 4; ++i) a[i] = ZE[(rg * 4 + i) * 68 + s];
        for (int i = 0; i < 4; ++i) for (int j = 0; j < 8; ++j)
            acc[i][j] = fmaf(a[i], b[j], acc[i][j]);
    }
    for (int i = 0; i < 4; ++i) for (int j = 0; j < 8; ++j) {
        int n = cg * 8 + j;
        H0[(rg * 4 + i) * 257 + n] = softplus_fast(acc[i][j] + tval * W0[n * 65] + b0[n]);
    }
    __syncthreads();

    for (int idx = tid; idx < FRB * 16; idx += FNT) {
        int r = idx >> 4, c = idx & 15;
        *(float4*)(&ZE[r * 68 + c * 4]) = *(const float4*)(e + (rowbase + r) * 64 + c * 4);
    }

    for (int i = 0; i < 4; ++i) for (int j = 0; j < 8; ++j) acc[i][j] = 0.0f;
    for (int s = 0; s < 256; ++s) {
        float b[8];
        for (int j = 0; j < 8; ++j) b[j] = W1[(cg * 8 + j) * 257 + 1 + s];
        float a[4];
        for (int i = 0; i < 4; ++i) a[i] = H0[(rg * 4 + i) * 257 + s];
        for (int i = 0; i < 4; ++i) for (int j = 0; j < 8; ++j)
            acc[i][j] = fmaf(a[i], b[j], acc[i][j]);
    }
    for (int i = 0; i < 4; ++i) for (int j = 0; j < 8; ++j) {
        int n = cg * 8 + j;
        H1[(rg * 4 + i) * 257 + n] = softplus_fast(acc[i][j] + tval * W1[n * 257] + b1[n]);
    }
    __syncthreads();

    for (int i = 0; i < 2; ++i) for (int j = 0; j < 4; ++j) acc2[i][j] = 0.0f;
    for (int s = 0; s < 256; ++s) {
        float b[4];
        for (int j = 0; j < 4; ++j) b[j] = W2[(cg2 * 4 + j) * 257 + 1 + s];
        float a[2];
        for (int i = 0; i < 2; ++i) a[i] = H1[(rg2 * 2 + i) * 257 + s];
        for (int i = 0; i < 2; ++i) for (int j = 0; j < 4; ++j)
            acc2[i][j] = fmaf(a[i], b[j], acc2[i][j]);
    }
    for (int i = 0; i < 2; ++i) for (int j = 0; j < 4; ++j) {
        int n = cg2 * 4 + j;
        out[(rowbase + rg2 * 2 + i) * 65 + n] = acc2[i][j] + tval * W2[n * 257] + b2[n];
    }
    __syncthreads();

    for (int i = 0; i < 4; ++i) for (int j = 0; j < 8; ++j) acc[i][j] = 0.0f;
    for (int s = 0; s < 64; ++s) {
        float b[8];
        for (int j = 0; j < 8; ++j) b[j] = W2[s * 257 + 1 + cg * 8 + j];
        float a[4];
        for (int i = 0; i < 4; ++i) a[i] = ZE[(rg * 4 + i) * 68 + s];
        for (int i = 0; i < 4; ++i) for (int j = 0; j < 8; ++j)
            acc[i][j] = fmaf(a[i], b[j], acc[i][j]);
    }
    for (int i = 0; i < 4; ++i) for (int j = 0; j < 8; ++j) {
        int r = rg * 4 + i, n = cg * 8 + j;
        float h = H1[r * 257 + n];
        H1[r * 257 + n] = acc[i][j] * (1.0f - __expf(-h));
    }
    __syncthreads();

    for (int i = 0; i < 4; ++i) for (int j = 0; j < 8; ++j) acc[i][j] = 0.0f;
    for (int s = 0; s < 256; ++s) {
        float b[8];
        for (int j = 0; j < 8; ++j) b[j] = W1[s * 257 + 1 + cg * 8 + j];
        float a[4];
        for (int i = 0; i < 4; ++i) a[i] = H1[(rg * 4 + i) * 257 + s];
        for (int i = 0; i < 4; ++i) for (int j = 0; j < 8; ++j)
            acc[i][j] = fmaf(a[i], b[j], acc[i][j]);
    }
    for (int i = 0; i < 4; ++i) for (int j = 0; j < 8; ++j) {
        int r = rg * 4 + i, n = cg * 8 + j;
        float h = H0[r * 257 + n];
        H0[r * 257 + n] = acc[i][j] * (1.0f - __expf(-h));
    }
    __syncthreads();

    for (int i = 0; i < 2; ++i) for (int j = 0; j < 4; ++j) acc2[i][j] = 0.0f;
    for (int s = 0; s < 256; ++s) {
        float b[4];
        for (int j = 0; j < 4; ++j) b[j] = W0[s * 65 + 1 + cg2 * 4 + j];
        float a[2];
        for (int i = 0; i < 2; ++i) a[i] = H0[(rg2 * 2 + i) * 257 + s];
        for (int i = 0; i < 2; ++i) for (int j = 0; j < 4; ++j)
            acc2[i][j] = fmaf(a[i], b[j], acc2[i][j]);
    }
    float pA = 0.0f, pB = 0.0f;
    for (int j = 0; j < 4; ++j) {
        int n = cg2 * 4 + j;
        pA = fmaf(acc2[0][j], ZE[(rg2 * 2 + 0) * 68 + n], pA);
        pB = fmaf(acc2[1][j], ZE[(rg2 * 2 + 1) * 68 + n], pB);
    }
    for (int off = 8; off > 0; off >>= 1) {
        pA += __shfl_down(pA, off, 16);
        pB += __shfl_down(pB, off, 16);
    }
    if (cg2 == 0) {
        out[(rowbase + rg2 * 2 + 0) * 65 + 64] = -pA;
        out[(rowbase + rg2 * 2 + 1) * 65 + 64] = -pB;
    }
}

extern "C" void kernel_launch(void* const* d_in, const int* in_sizes, int n_in,
                              void* d_out, int out_size, void* d_ws, size_t ws_size,
                              hipStream_t stream)
{
    const float* t  = (const float*)d_in[0];
    const float* y  = (const float*)d_in[1];
    const float* e  = (const float*)d_in[2];
    const float* W0 = (const float*)d_in[3];
    const float* b0 = (const float*)d_in[4];
    const float* W1 = (const float*)d_in[5];
    const float* b1 = (const float*)d_in[6];
    const float* W2 = (const float*)d_in[7];
    const float* b2 = (const float*)d_in[8];
    float* out = (float*)d_out;

    const int B = in_sizes[1] / 65;

    if (ws_size >= (size_t)WS_BYTES) {
        prep_pack<<<(PACK_ELEMS + 576 + 255) / 256, 256, 0, stream>>>(
            t, W0, b0, W1, b1, W2, b2, (short*)d_ws);
        ode_mfma<<<B / RB, NT, 0, stream>>>(y, e, (const short*)d_ws, out);
    } else {
        ode_fallback<<<B / FRB, FNT, 0, stream>>>(t, y, e, W0, b0, W1, b1, W2, b2, out);
    }
}